// Round 7
// baseline (1019.072 us; speedup 1.0000x reference)
//
#include <hip/hip_runtime.h>
#include <hip/hip_fp16.h>
#include <stdint.h>

// 25-qubit, 8-layer RY + CNOT-chain circuit, output <Z_q0>.
// CNOT chains deferred into a GF(2) change-of-basis; only 200 RYs touch the
// state (2^25 fp16 = 64 MiB in d_ws). Arithmetic in f32.
// Round 7: LDS exchanges in fp16 -> 64 KiB LDS -> 2 blocks/CU (32 waves,
// full occupancy). Block B's gathers/compute now fill block A's barrier and
// load-latency bubbles. kpassB: R0->R1 writer packs 8 halves per b128 (hswz
// keeps 16B groups + balanced banks); readers ds_read_u16 (2-way max = free).
// kpassA exchange: lane-paired dword writes (shfl_xor(1)), natural layout is
// conflict-free. Also removed the provably-unneeded R1 read->writeback
// barrier in kpassB (threads write back exactly their own read slots).

#define NQ 25
#define DEPTH 8

struct MaskSet {
  uint32_t M[DEPTH][NQ];   // M[l][b] = column b of W_l (pairing masks)
  uint32_t F[DEPTH][NQ];   // F[l][b] = row b of W_l^-1 (orientation functionals)
  uint32_t fz;             // final Z functional (row 24 of W_8^-1)
};

__host__ __device__ constexpr MaskSet buildMasks() {
  MaskSet r{};
  uint32_t col[NQ] = {}, inv[NQ] = {};
  for (int j = 0; j < NQ; ++j) { col[j] = 1u << j; inv[j] = 1u << j; }
  for (int l = 0; l < DEPTH; ++l) {
    for (int b = 0; b < NQ; ++b) { r.M[l][b] = col[b]; r.F[l][b] = inv[b]; }
    for (int w = 0; w < NQ - 1; ++w) {   // CNOT chain of layer l
      const int cb = 24 - w, tb = 23 - w;
      col[cb] ^= col[tb];
      inv[tb] ^= inv[cb];
    }
  }
  r.fz = inv[24];
  return r;
}

constexpr MaskSet MK = buildMasks();

// Half-index swizzle for kpassB LDS (2^15 halves = 64 KiB): XOR bits 3..5
// with bits 6..8. Linear over GF(2); preserves 8-half (16B) groups.
__host__ __device__ constexpr uint32_t hswz(uint32_t h) { return h ^ ((h >> 3) & 0x38u); }

__host__ __device__ constexpr uint32_t kxorB(int L, int d0, uint32_t y) {
  uint32_t a = 0;
  for (int i = 0; i < 5; ++i) if ((y >> i) & 1u) a ^= MK.M[L][d0 + i];
  return a;
}

__host__ __device__ constexpr uint32_t cpar(uint32_t x) {
  uint32_t p = 0;
  for (int i = 0; i < 32; ++i) p ^= (x >> i) & 1u;
  return p;
}

// Evenness functional for R2's low-bit: bit0 of B2(t) = parity(t & r2mask(L)).
__host__ __device__ constexpr uint32_t r2mask(int L) {
  uint32_t r = 0;
  for (int i = 0; i < 5; ++i) {
    r |= (MK.M[L][i] & 1u) << i;           // t bits 0..4 -> dims 0..4
    r |= (MK.M[L][5 + i] & 1u) << (5 + i); // t bits 5..9 -> dims 5..9
  }
  return r;
}

__device__ __forceinline__ uint32_t pkh(float a, float b) {
  __half2 h = __floats2half2_rn(a, b);   // round-to-nearest (unbiased)
  return __builtin_bit_cast(uint32_t, h);
}
__device__ __forceinline__ float2 uph(uint32_t w) {
  __half2 h = __builtin_bit_cast(__half2, w);
  return __half22float2(h);
}
__device__ __forceinline__ float h2fu(uint32_t x) {   // low 16 bits -> f32
  __half h = __builtin_bit_cast(__half, (uint16_t)(x & 0xffffu));
  return __half2float(h);
}
__device__ __forceinline__ float h2fs(uint16_t x) {
  __half h = __builtin_bit_cast(__half, x);
  return __half2float(h);
}
__device__ __forceinline__ uint16_t f2hs(float x) {
  __half h = __float2half_rn(x);
  return __builtin_bit_cast(uint16_t, h);
}

__global__ void kprep(const float* __restrict__ theta, float* __restrict__ trig,
                      float* __restrict__ outp)
{
  int t = threadIdx.x;
  if (t == 0) outp[0] = 0.0f;
  if (t < 200) {
    int l = t / 25, b = t % 25;            // b = bit position, qubit w = 24-b
    float th = theta[l * 25 + (24 - b)] * 0.5f;
    trig[2 * t]     = cosf(th);
    trig[2 * t + 1] = sinf(th);
  }
}

// ---- passB tail: R0 (dims 0..4, v in tile-address order) -> fp16 LDS ->
//      R1 -> writeback -> R2 -> merged full-wave fp16 dword stores.
template<int L>
__device__ __forceinline__ void passB_tail(float (&v)[32], uint16_t* ldsH,
                                           const uint32_t t, const uint32_t bb,
                                           const float* __restrict__ trig,
                                           uint16_t* __restrict__ stateH)
{
  const float2* cs = (const float2*)(trig + 50 * L);
  // R0: dims 0..4. Element o <-> address bb|(t<<5)|o.
#pragma unroll
  for (int j = 0; j < 5; ++j) {
    const float2 w = cs[j];
    const float c = w.x, s = w.y;
    const uint32_t mu = MK.M[L][j];            // within bits 0..4
    const uint32_t fj = MK.F[L][j];
    const float se = (__builtin_popcount((bb | (t << 5)) & fj) & 1) ? -s : s;
#pragma unroll
    for (uint32_t o = 0; o < 32; ++o) {
      if (__builtin_popcount(o & fj & 31u) & 1) continue;   // compile-time
      const uint32_t o2 = o ^ mu;
      const float a0 = v[o], a1 = v[o2];
      v[o]  = c * a0 - se * a1;
      v[o2] = c * a1 + se * a0;
    }
  }
  // exchange 1: own segment, 8 halves per b128 (hswz layout), 4 insts
  {
    uint4* l4 = (uint4*)ldsH;
#pragma unroll
    for (uint32_t k = 0; k < 4; ++k) {
      uint4 q = { pkh(v[8*k+0], v[8*k+1]), pkh(v[8*k+2], v[8*k+3]),
                  pkh(v[8*k+4], v[8*k+5]), pkh(v[8*k+6], v[8*k+7]) };
      l4[hswz((t << 5) + 8u * k) >> 3] = q;
    }
  }
  __syncthreads();
  // R1: dims 5..9; thread coords: dims 0..4 <- t bits 0..4, dims 10..14 <- t bits 5..9
  uint32_t B1 = 0u;
#pragma unroll
  for (int i = 0; i < 5; ++i) B1 ^= ((t >> i) & 1u) ? MK.M[L][i] : 0u;
#pragma unroll
  for (int i = 0; i < 5; ++i) B1 ^= ((t >> (5 + i)) & 1u) ? MK.M[L][10 + i] : 0u;
  const uint32_t B1s = hswz(B1);
#pragma unroll
  for (uint32_t y = 0; y < 32; ++y) v[y] = h2fs(ldsH[B1s ^ hswz(kxorB(L, 5, y))]);
#pragma unroll
  for (int j = 0; j < 5; ++j) {
    const float2 w = cs[5 + j];
    const float c = w.x, s = w.y;
    const float se = (__builtin_popcount(bb & MK.F[L][5 + j]) & 1) ? -s : s;
#pragma unroll
    for (uint32_t y = 0; y < 32; ++y) {
      if ((y >> j) & 1u) continue;
      const uint32_t y2 = y | (1u << j);
      const float a0 = v[y], a1 = v[y2];
      v[y]  = c * a0 - se * a1;
      v[y2] = c * a1 + se * a0;
    }
  }
  // writeback to own read slots — no barrier needed before (slot sets are
  // disjoint per thread; each thread writes only what it read)
#pragma unroll
  for (uint32_t y = 0; y < 32; ++y) ldsH[B1s ^ hswz(kxorB(L, 5, y))] = f2hs(v[y]);
  __syncthreads();
  // R2: dims 10..14; thread coords: dims 0..4 <- t bits 0..4, dims 5..9 <- t bits 5..9
  uint32_t B2 = 0u;
#pragma unroll
  for (int i = 0; i < 5; ++i) B2 ^= ((t >> i) & 1u) ? MK.M[L][i] : 0u;
#pragma unroll
  for (int i = 0; i < 5; ++i) B2 ^= ((t >> (5 + i)) & 1u) ? MK.M[L][5 + i] : 0u;
  const uint32_t B2s = hswz(B2);
#pragma unroll
  for (uint32_t y = 0; y < 32; ++y) v[y] = h2fs(ldsH[B2s ^ hswz(kxorB(L, 10, y))]);
#pragma unroll
  for (int j = 0; j < 5; ++j) {
    const float2 w = cs[10 + j];
    const float c = w.x, s = w.y;
    const float se = (__builtin_popcount(bb & MK.F[L][10 + j]) & 1) ? -s : s;
#pragma unroll
    for (uint32_t y = 0; y < 32; ++y) {
      if ((y >> j) & 1u) continue;
      const uint32_t y2 = y | (1u << j);
      const float a0 = v[y], a1 = v[y2];
      v[y]  = c * a0 - se * a1;
      v[y2] = c * a1 + se * a0;
    }
  }
  // merged store: pair (y, y^1) via M[L][10]; cls = bit0 of own address;
  // partner lane = t^1 (M[L][0]=e0). One unpredicated 64-lane dword store
  // per pair = full 128B-line coverage.
  {
    constexpr uint32_t rm = r2mask(L);
    const uint32_t cls = (uint32_t)__builtin_popcount(t & rm) & 1u;
    const uint32_t sb = bb ^ B2;
#pragma unroll
    for (uint32_t yp = 0; yp < 32; yp += 2) {
      const float p0 = __shfl_xor(v[yp], 1, 64);
      const float p1 = __shfl_xor(v[yp + 1], 1, 64);
      const uint32_t ad = (sb ^ kxorB(L, 10, yp) ^ (cls ? MK.M[L][10] : 0u)) & ~1u;
      const uint32_t val = cls ? pkh(p1, v[yp + 1]) : pkh(v[yp], p0);
      *(uint32_t*)(stateH + ad) = val;
    }
  }
}

template<int L>
__global__ __launch_bounds__(1024, 8) void kpassB(uint16_t* __restrict__ stateH,
                                                  const float* __restrict__ trig)
{
  __shared__ __align__(16) uint16_t ldsH[32768];   // 64 KiB -> 2 blocks/CU
  const uint32_t t = threadIdx.x;
  const uint32_t bb = (uint32_t)blockIdx.x << 15;
  // direct load: thread t owns 64 contiguous bytes (32 halves, tile order)
  float v[32];
  {
    const uint4* g4 = (const uint4*)(stateH + bb + (t << 5));
#pragma unroll
    for (uint32_t k = 0; k < 4; ++k) {
      const uint4 q = g4[k];
      float2 f;
      f = uph(q.x); v[8*k+0] = f.x; v[8*k+1] = f.y;
      f = uph(q.y); v[8*k+2] = f.x; v[8*k+3] = f.y;
      f = uph(q.z); v[8*k+4] = f.x; v[8*k+5] = f.y;
      f = uph(q.w); v[8*k+6] = f.x; v[8*k+7] = f.y;
    }
  }
  passB_tail<L>(v, ldsH, t, bb, trig, stateH);
}

// kinit: layer-0 product state built analytically in tile-address order
// (62 mults), then layer-1 passB tail. Write-only pass.
__global__ __launch_bounds__(1024, 8) void kinit(uint16_t* __restrict__ stateH,
                                                 const float* __restrict__ trig)
{
  __shared__ __align__(16) uint16_t ldsH[32768];
  const uint32_t t = threadIdx.x;
  const uint32_t bb = (uint32_t)blockIdx.x << 15;
  const float2* cs0 = (const float2*)trig;       // layer 0, indexed by bit
  const uint32_t hi = bb | (t << 5);
  float pt = 1.0f;
#pragma unroll
  for (int b = 5; b < 25; ++b) {
    const float2 w = cs0[b];
    pt *= ((hi >> b) & 1u) ? w.y : w.x;
  }
  float v[32];
  v[0] = pt;
#pragma unroll
  for (int j = 0; j < 5; ++j) {
    const float2 w = cs0[j];
#pragma unroll
    for (int o = 0; o < (1 << j); ++o) {
      v[o | (1 << j)] = v[o] * w.y;
      v[o]            = v[o] * w.x;
    }
  }
  passB_tail<1>(v, ldsH, t, bb, trig, stateH);
}

// ---- passA: pivots 15..24. Block = 32 contiguous spectators (slo) x 1024
// combos. Merged dword gathers/stores (lane-pairing), one fp16 LDS exchange
// (lane-paired dword writes; natural layout is bank-conflict-free).
template<int L, bool FIN>
__global__ __launch_bounds__(1024, 8) void kpassA(uint16_t* __restrict__ stateH,
                                                  const float* __restrict__ trig,
                                                  float* __restrict__ outp)
{
  __shared__ __align__(16) uint16_t ldsH[32768];   // 64 KiB -> 2 blocks/CU
  __shared__ float wsum[16];
  const uint32_t t = threadIdx.x;
  const uint32_t sbase = (uint32_t)blockIdx.x << 5;   // bits 5..14
  const float2* cs = (const float2*)(trig + 50 * L) + 15;
  const uint32_t slo = t & 31u;
  const uint32_t yf  = t >> 5;
  const uint32_t odd = t & 1u;
  // R0: register dims = pivots 15..19; yf -> pivots 20..24.
  uint32_t cy = 0u;
#pragma unroll
  for (int k = 0; k < 5; ++k) cy ^= ((yf >> k) & 1u) ? MK.M[L][20 + k] : 0u;
  const uint32_t A0 = sbase ^ slo ^ cy;
  float v[32];
  // merged gathers: pair (x, x^1) via M[L][15]; shfl_xor(1) redistributes.
#pragma unroll
  for (uint32_t xp = 0; xp < 32; xp += 2) {
    const uint32_t ax = (A0 ^ kxorB(L, 15, xp) ^ (odd ? MK.M[L][15] : 0u)) & ~1u;
    const uint32_t d  = *(const uint32_t*)(stateH + ax);
    const uint32_t dp = __shfl_xor(d, 1, 64);
    v[xp]     = h2fu(odd ? (dp >> 16) : d);
    v[xp + 1] = h2fu(odd ? (d >> 16)  : dp);
  }
#pragma unroll
  for (int j = 0; j < 5; ++j) {
    const float2 w = cs[j];
    const float c = w.x, s = w.y;
#pragma unroll
    for (uint32_t x = 0; x < 32; ++x) {
      if ((x >> j) & 1u) continue;
      const uint32_t x2 = x | (1u << j);
      const float a0 = v[x], a1 = v[x2];
      v[x]  = c * a0 - s * a1;
      v[x2] = s * a0 + c * a1;
    }
  }
  // exchange write: slot half-index = (yf<<10)|(x<<5)|slo. Lane pair
  // (slo, slo^1) packs one dword; even lanes handle x, odd lanes x+1:
  // 16 unpredicated full-wave dword LDS writes, 2-way banks max (free).
#pragma unroll
  for (uint32_t xp = 0; xp < 32; xp += 2) {
    const float p0 = __shfl_xor(v[xp], 1, 64);
    const float p1 = __shfl_xor(v[xp + 1], 1, 64);
    const uint32_t xm = xp + odd;
    const uint32_t val = odd ? pkh(p1, v[xp + 1]) : pkh(v[xp], p0);
    *(uint32_t*)(ldsH + ((yf << 10) + (xm << 5) + (slo & ~1u))) = val;
  }
  __syncthreads();
  // R1: register dims = pivots 20..24; yf -> pivots 15..19.
  uint32_t cumt = 0u;
#pragma unroll
  for (int k = 0; k < 5; ++k) cumt ^= ((yf >> k) & 1u) ? MK.M[L][15 + k] : 0u;
  const uint32_t Ab = sbase ^ slo ^ cumt;
#pragma unroll
  for (uint32_t x = 0; x < 32; ++x)
    v[x] = h2fs(ldsH[(x << 10) + (yf << 5) + slo]);
#pragma unroll
  for (int j = 0; j < 5; ++j) {
    const float2 w = cs[5 + j];
    const float c = w.x, s = w.y;
#pragma unroll
    for (uint32_t x = 0; x < 32; ++x) {
      if ((x >> j) & 1u) continue;
      const uint32_t x2 = x | (1u << j);
      const float a0 = v[x], a1 = v[x2];
      v[x]  = c * a0 - s * a1;
      v[x2] = s * a0 + c * a1;
    }
  }
  if (!FIN) {
    // merged stores: pair (x, x^1) via M[L][20]; even lanes store x-dword,
    // odd lanes x^1-dword; one unpredicated 64-lane store per pair.
#pragma unroll
    for (uint32_t xp = 0; xp < 32; xp += 2) {
      const float p0 = __shfl_xor(v[xp], 1, 64);
      const float p1 = __shfl_xor(v[xp + 1], 1, 64);
      const uint32_t ad = (Ab ^ kxorB(L, 20, xp) ^ (odd ? MK.M[L][20] : 0u)) & ~1u;
      const uint32_t val = odd ? pkh(p1, v[xp + 1]) : pkh(v[xp], p0);
      *(uint32_t*)(stateH + ad) = val;
    }
  } else {
    constexpr uint32_t pz =
        (cpar(MK.M[L][20] & MK.fz) << 0) | (cpar(MK.M[L][21] & MK.fz) << 1) |
        (cpar(MK.M[L][22] & MK.fz) << 2) | (cpar(MK.M[L][23] & MK.fz) << 3) |
        (cpar(MK.M[L][24] & MK.fz) << 4);
    float acc = 0.0f;
#pragma unroll
    for (uint32_t x = 0; x < 32; ++x) {
      const float q = v[x] * v[x];
      acc += cpar(x & pz) ? -q : q;
    }
    if (__builtin_popcount(Ab & MK.fz) & 1) acc = -acc;
#pragma unroll
    for (int off = 32; off >= 1; off >>= 1) acc += __shfl_down(acc, off, 64);
    if ((t & 63u) == 0u) wsum[t >> 6] = acc;
    __syncthreads();
    if (t == 0) {
      float ssum = 0.0f;
#pragma unroll
      for (int w2 = 0; w2 < 16; ++w2) ssum += wsum[w2];
      atomicAdd(outp, ssum);
    }
  }
}

extern "C" void kernel_launch(void* const* d_in, const int* in_sizes, int n_in,
                              void* d_out, int out_size, void* d_ws, size_t ws_size,
                              hipStream_t stream)
{
  (void)in_sizes; (void)n_in; (void)out_size; (void)ws_size;
  const float* theta = (const float*)d_in[0];
  float* outp  = (float*)d_out;
  uint16_t* stateH = (uint16_t*)d_ws;                              // 2^25 halves
  float* trig  = (float*)((char*)d_ws + (size_t)(1u << 25) * 2u);  // 400 floats

  kprep<<<1, 256, 0, stream>>>(theta, trig, outp);
  kinit<<<1024, 1024, 0, stream>>>(stateH, trig);
  kpassA<1, false><<<1024, 1024, 0, stream>>>(stateH, trig, outp);
  kpassB<2><<<1024, 1024, 0, stream>>>(stateH, trig);
  kpassA<2, false><<<1024, 1024, 0, stream>>>(stateH, trig, outp);
  kpassB<3><<<1024, 1024, 0, stream>>>(stateH, trig);
  kpassA<3, false><<<1024, 1024, 0, stream>>>(stateH, trig, outp);
  kpassB<4><<<1024, 1024, 0, stream>>>(stateH, trig);
  kpassA<4, false><<<1024, 1024, 0, stream>>>(stateH, trig, outp);
  kpassB<5><<<1024, 1024, 0, stream>>>(stateH, trig);
  kpassA<5, false><<<1024, 1024, 0, stream>>>(stateH, trig, outp);
  kpassB<6><<<1024, 1024, 0, stream>>>(stateH, trig);
  kpassA<6, false><<<1024, 1024, 0, stream>>>(stateH, trig, outp);
  kpassB<7><<<1024, 1024, 0, stream>>>(stateH, trig);
  kpassA<7, true><<<1024, 1024, 0, stream>>>(stateH, trig, outp);
}

// Round 8
// 792.154 us; speedup vs baseline: 1.2865x; 1.2865x over previous
//
#include <hip/hip_runtime.h>
#include <hip/hip_fp16.h>
#include <stdint.h>

// 25-qubit, 8-layer RY + CNOT-chain circuit, output <Z_q0>.
// CNOT chains deferred into a GF(2) change-of-basis; only 200 RYs touch the
// state (2^25 fp16 = 64 MiB in d_ws). Arithmetic in f32.
// Round 8: round-7 structure (fp16 LDS exchanges -> 64 KiB -> 2 blocks/CU)
// but __launch_bounds__(1024,4): the (1024,8) 64-VGPR hard cap made the
// allocator spill v[32] to scratch (VGPR=32, WRITE_SIZE 6x, VALUBusy 1%).
// With cap 128 the kernel uses ~52-60 VGPRs (<=64), so hardware still
// co-schedules 2 blocks/CU (LDS 64 KiB, 8 waves/SIMD) — occupancy from
// usage, not from the cap.

#define NQ 25
#define DEPTH 8

struct MaskSet {
  uint32_t M[DEPTH][NQ];   // M[l][b] = column b of W_l (pairing masks)
  uint32_t F[DEPTH][NQ];   // F[l][b] = row b of W_l^-1 (orientation functionals)
  uint32_t fz;             // final Z functional (row 24 of W_8^-1)
};

__host__ __device__ constexpr MaskSet buildMasks() {
  MaskSet r{};
  uint32_t col[NQ] = {}, inv[NQ] = {};
  for (int j = 0; j < NQ; ++j) { col[j] = 1u << j; inv[j] = 1u << j; }
  for (int l = 0; l < DEPTH; ++l) {
    for (int b = 0; b < NQ; ++b) { r.M[l][b] = col[b]; r.F[l][b] = inv[b]; }
    for (int w = 0; w < NQ - 1; ++w) {   // CNOT chain of layer l
      const int cb = 24 - w, tb = 23 - w;
      col[cb] ^= col[tb];
      inv[tb] ^= inv[cb];
    }
  }
  r.fz = inv[24];
  return r;
}

constexpr MaskSet MK = buildMasks();

// Half-index swizzle for kpassB LDS (2^15 halves = 64 KiB): XOR bits 3..5
// with bits 6..8. Linear over GF(2); preserves 8-half (16B) groups.
__host__ __device__ constexpr uint32_t hswz(uint32_t h) { return h ^ ((h >> 3) & 0x38u); }

__host__ __device__ constexpr uint32_t kxorB(int L, int d0, uint32_t y) {
  uint32_t a = 0;
  for (int i = 0; i < 5; ++i) if ((y >> i) & 1u) a ^= MK.M[L][d0 + i];
  return a;
}

__host__ __device__ constexpr uint32_t cpar(uint32_t x) {
  uint32_t p = 0;
  for (int i = 0; i < 32; ++i) p ^= (x >> i) & 1u;
  return p;
}

// Evenness functional for R2's low-bit: bit0 of B2(t) = parity(t & r2mask(L)).
__host__ __device__ constexpr uint32_t r2mask(int L) {
  uint32_t r = 0;
  for (int i = 0; i < 5; ++i) {
    r |= (MK.M[L][i] & 1u) << i;           // t bits 0..4 -> dims 0..4
    r |= (MK.M[L][5 + i] & 1u) << (5 + i); // t bits 5..9 -> dims 5..9
  }
  return r;
}

__device__ __forceinline__ uint32_t pkh(float a, float b) {
  __half2 h = __floats2half2_rn(a, b);   // round-to-nearest (unbiased)
  return __builtin_bit_cast(uint32_t, h);
}
__device__ __forceinline__ float2 uph(uint32_t w) {
  __half2 h = __builtin_bit_cast(__half2, w);
  return __half22float2(h);
}
__device__ __forceinline__ float h2fu(uint32_t x) {   // low 16 bits -> f32
  __half h = __builtin_bit_cast(__half, (uint16_t)(x & 0xffffu));
  return __half2float(h);
}
__device__ __forceinline__ float h2fs(uint16_t x) {
  __half h = __builtin_bit_cast(__half, x);
  return __half2float(h);
}
__device__ __forceinline__ uint16_t f2hs(float x) {
  __half h = __float2half_rn(x);
  return __builtin_bit_cast(uint16_t, h);
}

__global__ void kprep(const float* __restrict__ theta, float* __restrict__ trig,
                      float* __restrict__ outp)
{
  int t = threadIdx.x;
  if (t == 0) outp[0] = 0.0f;
  if (t < 200) {
    int l = t / 25, b = t % 25;            // b = bit position, qubit w = 24-b
    float th = theta[l * 25 + (24 - b)] * 0.5f;
    trig[2 * t]     = cosf(th);
    trig[2 * t + 1] = sinf(th);
  }
}

// ---- passB tail: R0 (dims 0..4, v in tile-address order) -> fp16 LDS ->
//      R1 -> writeback -> R2 -> merged full-wave fp16 dword stores.
template<int L>
__device__ __forceinline__ void passB_tail(float (&v)[32], uint16_t* ldsH,
                                           const uint32_t t, const uint32_t bb,
                                           const float* __restrict__ trig,
                                           uint16_t* __restrict__ stateH)
{
  const float2* cs = (const float2*)(trig + 50 * L);
  // R0: dims 0..4. Element o <-> address bb|(t<<5)|o.
#pragma unroll
  for (int j = 0; j < 5; ++j) {
    const float2 w = cs[j];
    const float c = w.x, s = w.y;
    const uint32_t mu = MK.M[L][j];            // within bits 0..4
    const uint32_t fj = MK.F[L][j];
    const float se = (__builtin_popcount((bb | (t << 5)) & fj) & 1) ? -s : s;
#pragma unroll
    for (uint32_t o = 0; o < 32; ++o) {
      if (__builtin_popcount(o & fj & 31u) & 1) continue;   // compile-time
      const uint32_t o2 = o ^ mu;
      const float a0 = v[o], a1 = v[o2];
      v[o]  = c * a0 - se * a1;
      v[o2] = c * a1 + se * a0;
    }
  }
  // exchange 1: own segment, 8 halves per b128 (hswz layout), 4 insts
  {
    uint4* l4 = (uint4*)ldsH;
#pragma unroll
    for (uint32_t k = 0; k < 4; ++k) {
      uint4 q = { pkh(v[8*k+0], v[8*k+1]), pkh(v[8*k+2], v[8*k+3]),
                  pkh(v[8*k+4], v[8*k+5]), pkh(v[8*k+6], v[8*k+7]) };
      l4[hswz((t << 5) + 8u * k) >> 3] = q;
    }
  }
  __syncthreads();
  // R1: dims 5..9; thread coords: dims 0..4 <- t bits 0..4, dims 10..14 <- t bits 5..9
  uint32_t B1 = 0u;
#pragma unroll
  for (int i = 0; i < 5; ++i) B1 ^= ((t >> i) & 1u) ? MK.M[L][i] : 0u;
#pragma unroll
  for (int i = 0; i < 5; ++i) B1 ^= ((t >> (5 + i)) & 1u) ? MK.M[L][10 + i] : 0u;
  const uint32_t B1s = hswz(B1);
#pragma unroll
  for (uint32_t y = 0; y < 32; ++y) v[y] = h2fs(ldsH[B1s ^ hswz(kxorB(L, 5, y))]);
#pragma unroll
  for (int j = 0; j < 5; ++j) {
    const float2 w = cs[5 + j];
    const float c = w.x, s = w.y;
    const float se = (__builtin_popcount(bb & MK.F[L][5 + j]) & 1) ? -s : s;
#pragma unroll
    for (uint32_t y = 0; y < 32; ++y) {
      if ((y >> j) & 1u) continue;
      const uint32_t y2 = y | (1u << j);
      const float a0 = v[y], a1 = v[y2];
      v[y]  = c * a0 - se * a1;
      v[y2] = c * a1 + se * a0;
    }
  }
  // writeback to own read slots — no barrier needed before (slot sets are
  // disjoint per thread; each thread writes only what it read)
#pragma unroll
  for (uint32_t y = 0; y < 32; ++y) ldsH[B1s ^ hswz(kxorB(L, 5, y))] = f2hs(v[y]);
  __syncthreads();
  // R2: dims 10..14; thread coords: dims 0..4 <- t bits 0..4, dims 5..9 <- t bits 5..9
  uint32_t B2 = 0u;
#pragma unroll
  for (int i = 0; i < 5; ++i) B2 ^= ((t >> i) & 1u) ? MK.M[L][i] : 0u;
#pragma unroll
  for (int i = 0; i < 5; ++i) B2 ^= ((t >> (5 + i)) & 1u) ? MK.M[L][5 + i] : 0u;
  const uint32_t B2s = hswz(B2);
#pragma unroll
  for (uint32_t y = 0; y < 32; ++y) v[y] = h2fs(ldsH[B2s ^ hswz(kxorB(L, 10, y))]);
#pragma unroll
  for (int j = 0; j < 5; ++j) {
    const float2 w = cs[10 + j];
    const float c = w.x, s = w.y;
    const float se = (__builtin_popcount(bb & MK.F[L][10 + j]) & 1) ? -s : s;
#pragma unroll
    for (uint32_t y = 0; y < 32; ++y) {
      if ((y >> j) & 1u) continue;
      const uint32_t y2 = y | (1u << j);
      const float a0 = v[y], a1 = v[y2];
      v[y]  = c * a0 - se * a1;
      v[y2] = c * a1 + se * a0;
    }
  }
  // merged store: pair (y, y^1) via M[L][10]; cls = bit0 of own address;
  // partner lane = t^1 (M[L][0]=e0). One unpredicated 64-lane dword store
  // per pair = full 128B-line coverage.
  {
    constexpr uint32_t rm = r2mask(L);
    const uint32_t cls = (uint32_t)__builtin_popcount(t & rm) & 1u;
    const uint32_t sb = bb ^ B2;
#pragma unroll
    for (uint32_t yp = 0; yp < 32; yp += 2) {
      const float p0 = __shfl_xor(v[yp], 1, 64);
      const float p1 = __shfl_xor(v[yp + 1], 1, 64);
      const uint32_t ad = (sb ^ kxorB(L, 10, yp) ^ (cls ? MK.M[L][10] : 0u)) & ~1u;
      const uint32_t val = cls ? pkh(p1, v[yp + 1]) : pkh(v[yp], p0);
      *(uint32_t*)(stateH + ad) = val;
    }
  }
}

template<int L>
__global__ __launch_bounds__(1024, 4) void kpassB(uint16_t* __restrict__ stateH,
                                                  const float* __restrict__ trig)
{
  __shared__ __align__(16) uint16_t ldsH[32768];   // 64 KiB -> 2 blocks/CU
  const uint32_t t = threadIdx.x;
  const uint32_t bb = (uint32_t)blockIdx.x << 15;
  // direct load: thread t owns 64 contiguous bytes (32 halves, tile order)
  float v[32];
  {
    const uint4* g4 = (const uint4*)(stateH + bb + (t << 5));
#pragma unroll
    for (uint32_t k = 0; k < 4; ++k) {
      const uint4 q = g4[k];
      float2 f;
      f = uph(q.x); v[8*k+0] = f.x; v[8*k+1] = f.y;
      f = uph(q.y); v[8*k+2] = f.x; v[8*k+3] = f.y;
      f = uph(q.z); v[8*k+4] = f.x; v[8*k+5] = f.y;
      f = uph(q.w); v[8*k+6] = f.x; v[8*k+7] = f.y;
    }
  }
  passB_tail<L>(v, ldsH, t, bb, trig, stateH);
}

// kinit: layer-0 product state built analytically in tile-address order
// (62 mults), then layer-1 passB tail. Write-only pass.
__global__ __launch_bounds__(1024, 4) void kinit(uint16_t* __restrict__ stateH,
                                                 const float* __restrict__ trig)
{
  __shared__ __align__(16) uint16_t ldsH[32768];
  const uint32_t t = threadIdx.x;
  const uint32_t bb = (uint32_t)blockIdx.x << 15;
  const float2* cs0 = (const float2*)trig;       // layer 0, indexed by bit
  const uint32_t hi = bb | (t << 5);
  float pt = 1.0f;
#pragma unroll
  for (int b = 5; b < 25; ++b) {
    const float2 w = cs0[b];
    pt *= ((hi >> b) & 1u) ? w.y : w.x;
  }
  float v[32];
  v[0] = pt;
#pragma unroll
  for (int j = 0; j < 5; ++j) {
    const float2 w = cs0[j];
#pragma unroll
    for (int o = 0; o < (1 << j); ++o) {
      v[o | (1 << j)] = v[o] * w.y;
      v[o]            = v[o] * w.x;
    }
  }
  passB_tail<1>(v, ldsH, t, bb, trig, stateH);
}

// ---- passA: pivots 15..24. Block = 32 contiguous spectators (slo) x 1024
// combos. Merged dword gathers/stores (lane-pairing), one fp16 LDS exchange
// (lane-paired dword writes; natural layout is bank-conflict-free).
template<int L, bool FIN>
__global__ __launch_bounds__(1024, 4) void kpassA(uint16_t* __restrict__ stateH,
                                                  const float* __restrict__ trig,
                                                  float* __restrict__ outp)
{
  __shared__ __align__(16) uint16_t ldsH[32768];   // 64 KiB -> 2 blocks/CU
  __shared__ float wsum[16];
  const uint32_t t = threadIdx.x;
  const uint32_t sbase = (uint32_t)blockIdx.x << 5;   // bits 5..14
  const float2* cs = (const float2*)(trig + 50 * L) + 15;
  const uint32_t slo = t & 31u;
  const uint32_t yf  = t >> 5;
  const uint32_t odd = t & 1u;
  // R0: register dims = pivots 15..19; yf -> pivots 20..24.
  uint32_t cy = 0u;
#pragma unroll
  for (int k = 0; k < 5; ++k) cy ^= ((yf >> k) & 1u) ? MK.M[L][20 + k] : 0u;
  const uint32_t A0 = sbase ^ slo ^ cy;
  float v[32];
  // merged gathers: pair (x, x^1) via M[L][15]; shfl_xor(1) redistributes.
#pragma unroll
  for (uint32_t xp = 0; xp < 32; xp += 2) {
    const uint32_t ax = (A0 ^ kxorB(L, 15, xp) ^ (odd ? MK.M[L][15] : 0u)) & ~1u;
    const uint32_t d  = *(const uint32_t*)(stateH + ax);
    const uint32_t dp = __shfl_xor(d, 1, 64);
    v[xp]     = h2fu(odd ? (dp >> 16) : d);
    v[xp + 1] = h2fu(odd ? (d >> 16)  : dp);
  }
#pragma unroll
  for (int j = 0; j < 5; ++j) {
    const float2 w = cs[j];
    const float c = w.x, s = w.y;
#pragma unroll
    for (uint32_t x = 0; x < 32; ++x) {
      if ((x >> j) & 1u) continue;
      const uint32_t x2 = x | (1u << j);
      const float a0 = v[x], a1 = v[x2];
      v[x]  = c * a0 - s * a1;
      v[x2] = s * a0 + c * a1;
    }
  }
  // exchange write: slot half-index = (yf<<10)|(x<<5)|slo. Lane pair
  // (slo, slo^1) packs one dword; even lanes handle x, odd lanes x+1:
  // 16 unpredicated full-wave dword LDS writes, 2-way banks max (free).
#pragma unroll
  for (uint32_t xp = 0; xp < 32; xp += 2) {
    const float p0 = __shfl_xor(v[xp], 1, 64);
    const float p1 = __shfl_xor(v[xp + 1], 1, 64);
    const uint32_t xm = xp + odd;
    const uint32_t val = odd ? pkh(p1, v[xp + 1]) : pkh(v[xp], p0);
    *(uint32_t*)(ldsH + ((yf << 10) + (xm << 5) + (slo & ~1u))) = val;
  }
  __syncthreads();
  // R1: register dims = pivots 20..24; yf -> pivots 15..19.
  uint32_t cumt = 0u;
#pragma unroll
  for (int k = 0; k < 5; ++k) cumt ^= ((yf >> k) & 1u) ? MK.M[L][15 + k] : 0u;
  const uint32_t Ab = sbase ^ slo ^ cumt;
#pragma unroll
  for (uint32_t x = 0; x < 32; ++x)
    v[x] = h2fs(ldsH[(x << 10) + (yf << 5) + slo]);
#pragma unroll
  for (int j = 0; j < 5; ++j) {
    const float2 w = cs[5 + j];
    const float c = w.x, s = w.y;
#pragma unroll
    for (uint32_t x = 0; x < 32; ++x) {
      if ((x >> j) & 1u) continue;
      const uint32_t x2 = x | (1u << j);
      const float a0 = v[x], a1 = v[x2];
      v[x]  = c * a0 - s * a1;
      v[x2] = s * a0 + c * a1;
    }
  }
  if (!FIN) {
    // merged stores: pair (x, x^1) via M[L][20]; even lanes store x-dword,
    // odd lanes x^1-dword; one unpredicated 64-lane store per pair.
#pragma unroll
    for (uint32_t xp = 0; xp < 32; xp += 2) {
      const float p0 = __shfl_xor(v[xp], 1, 64);
      const float p1 = __shfl_xor(v[xp + 1], 1, 64);
      const uint32_t ad = (Ab ^ kxorB(L, 20, xp) ^ (odd ? MK.M[L][20] : 0u)) & ~1u;
      const uint32_t val = odd ? pkh(p1, v[xp + 1]) : pkh(v[xp], p0);
      *(uint32_t*)(stateH + ad) = val;
    }
  } else {
    constexpr uint32_t pz =
        (cpar(MK.M[L][20] & MK.fz) << 0) | (cpar(MK.M[L][21] & MK.fz) << 1) |
        (cpar(MK.M[L][22] & MK.fz) << 2) | (cpar(MK.M[L][23] & MK.fz) << 3) |
        (cpar(MK.M[L][24] & MK.fz) << 4);
    float acc = 0.0f;
#pragma unroll
    for (uint32_t x = 0; x < 32; ++x) {
      const float q = v[x] * v[x];
      acc += cpar(x & pz) ? -q : q;
    }
    if (__builtin_popcount(Ab & MK.fz) & 1) acc = -acc;
#pragma unroll
    for (int off = 32; off >= 1; off >>= 1) acc += __shfl_down(acc, off, 64);
    if ((t & 63u) == 0u) wsum[t >> 6] = acc;
    __syncthreads();
    if (t == 0) {
      float ssum = 0.0f;
#pragma unroll
      for (int w2 = 0; w2 < 16; ++w2) ssum += wsum[w2];
      atomicAdd(outp, ssum);
    }
  }
}

extern "C" void kernel_launch(void* const* d_in, const int* in_sizes, int n_in,
                              void* d_out, int out_size, void* d_ws, size_t ws_size,
                              hipStream_t stream)
{
  (void)in_sizes; (void)n_in; (void)out_size; (void)ws_size;
  const float* theta = (const float*)d_in[0];
  float* outp  = (float*)d_out;
  uint16_t* stateH = (uint16_t*)d_ws;                              // 2^25 halves
  float* trig  = (float*)((char*)d_ws + (size_t)(1u << 25) * 2u);  // 400 floats

  kprep<<<1, 256, 0, stream>>>(theta, trig, outp);
  kinit<<<1024, 1024, 0, stream>>>(stateH, trig);
  kpassA<1, false><<<1024, 1024, 0, stream>>>(stateH, trig, outp);
  kpassB<2><<<1024, 1024, 0, stream>>>(stateH, trig);
  kpassA<2, false><<<1024, 1024, 0, stream>>>(stateH, trig, outp);
  kpassB<3><<<1024, 1024, 0, stream>>>(stateH, trig);
  kpassA<3, false><<<1024, 1024, 0, stream>>>(stateH, trig, outp);
  kpassB<4><<<1024, 1024, 0, stream>>>(stateH, trig);
  kpassA<4, false><<<1024, 1024, 0, stream>>>(stateH, trig, outp);
  kpassB<5><<<1024, 1024, 0, stream>>>(stateH, trig);
  kpassA<5, false><<<1024, 1024, 0, stream>>>(stateH, trig, outp);
  kpassB<6><<<1024, 1024, 0, stream>>>(stateH, trig);
  kpassA<6, false><<<1024, 1024, 0, stream>>>(stateH, trig, outp);
  kpassB<7><<<1024, 1024, 0, stream>>>(stateH, trig);
  kpassA<7, true><<<1024, 1024, 0, stream>>>(stateH, trig, outp);
}

// Round 9
// 680.929 us; speedup vs baseline: 1.4966x; 1.1633x over previous
//
#include <hip/hip_runtime.h>
#include <hip/hip_fp16.h>
#include <stdint.h>

// 25-qubit, 8-layer RY + CNOT-chain circuit, output <Z_q0>.
// CNOT chains deferred into a GF(2) change-of-basis; only 200 RYs touch the
// state (2^25 fp16 = 64 MiB in d_ws). Arithmetic in f32.
// Round 9: kpassB/kinit = round-6 form (f32 128-KiB LDS, VGPR 52, known
// good). ONLY kpassA changes: scalar fp16 LDS exchange (64 KiB -> 2
// blocks/CU co-residency to fill gather-latency + barrier bubbles). No
// packing shfls in the exchange (banks: reads broadcast-paired, writes
// 2-addr/bank = free), so register pressure stays ~round-6 (~50) and the
// allocator shouldn't resort to AGPR shuffling (round-8 failure mode).

#define NQ 25
#define DEPTH 8

struct MaskSet {
  uint32_t M[DEPTH][NQ];   // M[l][b] = column b of W_l (pairing masks)
  uint32_t F[DEPTH][NQ];   // F[l][b] = row b of W_l^-1 (orientation functionals)
  uint32_t fz;             // final Z functional (row 24 of W_8^-1)
};

__host__ __device__ constexpr MaskSet buildMasks() {
  MaskSet r{};
  uint32_t col[NQ] = {}, inv[NQ] = {};
  for (int j = 0; j < NQ; ++j) { col[j] = 1u << j; inv[j] = 1u << j; }
  for (int l = 0; l < DEPTH; ++l) {
    for (int b = 0; b < NQ; ++b) { r.M[l][b] = col[b]; r.F[l][b] = inv[b]; }
    for (int w = 0; w < NQ - 1; ++w) {   // CNOT chain of layer l
      const int cb = 24 - w, tb = 23 - w;
      col[cb] ^= col[tb];
      inv[tb] ^= inv[cb];
    }
  }
  r.fz = inv[24];
  return r;
}

constexpr MaskSet MK = buildMasks();

// f32 LDS swizzle for kpassB (2^15 floats = 128 KiB): XOR slot bits 2..4
// with owner bits 5..7. Preserves 16B groups -> b128-friendly.
__host__ __device__ constexpr uint32_t cswz(uint32_t a) { return a ^ ((a >> 3) & 28u); }

__host__ __device__ constexpr uint32_t kxorB(int L, int d0, uint32_t y) {
  uint32_t a = 0;
  for (int i = 0; i < 5; ++i) if ((y >> i) & 1u) a ^= MK.M[L][d0 + i];
  return a;
}

__host__ __device__ constexpr uint32_t cpar(uint32_t x) {
  uint32_t p = 0;
  for (int i = 0; i < 32; ++i) p ^= (x >> i) & 1u;
  return p;
}

// Evenness functional for R2's low-bit: bit0 of B2(t) = parity(t & r2mask(L)).
__host__ __device__ constexpr uint32_t r2mask(int L) {
  uint32_t r = 0;
  for (int i = 0; i < 5; ++i) {
    r |= (MK.M[L][i] & 1u) << i;           // t bits 0..4 -> dims 0..4
    r |= (MK.M[L][5 + i] & 1u) << (5 + i); // t bits 5..9 -> dims 5..9
  }
  return r;
}

__device__ __forceinline__ uint32_t pkh(float a, float b) {
  __half2 h = __floats2half2_rn(a, b);   // round-to-nearest (unbiased)
  return __builtin_bit_cast(uint32_t, h);
}
__device__ __forceinline__ float2 uph(uint32_t w) {
  __half2 h = __builtin_bit_cast(__half2, w);
  return __half22float2(h);
}
__device__ __forceinline__ float h2fu(uint32_t x) {   // low 16 bits -> f32
  __half h = __builtin_bit_cast(__half, (uint16_t)(x & 0xffffu));
  return __half2float(h);
}
__device__ __forceinline__ float h2fs(uint16_t x) {
  __half h = __builtin_bit_cast(__half, x);
  return __half2float(h);
}
__device__ __forceinline__ uint16_t f2hs(float x) {
  __half h = __float2half_rn(x);
  return __builtin_bit_cast(uint16_t, h);
}

__global__ void kprep(const float* __restrict__ theta, float* __restrict__ trig,
                      float* __restrict__ outp)
{
  int t = threadIdx.x;
  if (t == 0) outp[0] = 0.0f;
  if (t < 200) {
    int l = t / 25, b = t % 25;            // b = bit position, qubit w = 24-b
    float th = theta[l * 25 + (24 - b)] * 0.5f;
    trig[2 * t]     = cosf(th);
    trig[2 * t + 1] = sinf(th);
  }
}

// ---- passB tail (round-6 form): R0 -> f32 LDS -> R1 -> writeback ->
//      R2 -> merged full-wave fp16 dword stores.
template<int L>
__device__ __forceinline__ void passB_tail(float (&v)[32], float* lds,
                                           const uint32_t t, const uint32_t bb,
                                           const float* __restrict__ trig,
                                           uint16_t* __restrict__ stateH)
{
  const float2* cs = (const float2*)(trig + 50 * L);
  // R0: dims 0..4. Element o <-> address bb|(t<<5)|o.
#pragma unroll
  for (int j = 0; j < 5; ++j) {
    const float2 w = cs[j];
    const float c = w.x, s = w.y;
    const uint32_t mu = MK.M[L][j];            // within bits 0..4
    const uint32_t fj = MK.F[L][j];
    const float se = (__builtin_popcount((bb | (t << 5)) & fj) & 1) ? -s : s;
#pragma unroll
    for (uint32_t o = 0; o < 32; ++o) {
      if (__builtin_popcount(o & fj & 31u) & 1) continue;   // compile-time
      const uint32_t o2 = o ^ mu;
      const float a0 = v[o], a1 = v[o2];
      v[o]  = c * a0 - se * a1;
      v[o2] = c * a1 + se * a0;
    }
  }
  // exchange 1: write own segment (b128, cswz layout, f32)
  {
    float4* l4 = (float4*)lds;
#pragma unroll
    for (uint32_t k = 0; k < 8; ++k) {
      float4 q = { v[4*k], v[4*k+1], v[4*k+2], v[4*k+3] };
      l4[cswz((t << 5) + 4u * k) >> 2] = q;
    }
  }
  __syncthreads();
  // R1: dims 5..9; thread coords: dims 0..4 <- t bits 0..4, dims 10..14 <- t bits 5..9
  uint32_t B1 = 0u;
#pragma unroll
  for (int i = 0; i < 5; ++i) B1 ^= ((t >> i) & 1u) ? MK.M[L][i] : 0u;
#pragma unroll
  for (int i = 0; i < 5; ++i) B1 ^= ((t >> (5 + i)) & 1u) ? MK.M[L][10 + i] : 0u;
  const uint32_t B1s = cswz(B1);
#pragma unroll
  for (uint32_t y = 0; y < 32; ++y) v[y] = lds[B1s ^ cswz(kxorB(L, 5, y))];
#pragma unroll
  for (int j = 0; j < 5; ++j) {
    const float2 w = cs[5 + j];
    const float c = w.x, s = w.y;
    const float se = (__builtin_popcount(bb & MK.F[L][5 + j]) & 1) ? -s : s;
#pragma unroll
    for (uint32_t y = 0; y < 32; ++y) {
      if ((y >> j) & 1u) continue;
      const uint32_t y2 = y | (1u << j);
      const float a0 = v[y], a1 = v[y2];
      v[y]  = c * a0 - se * a1;
      v[y2] = c * a1 + se * a0;
    }
  }
  __syncthreads();   // protect re-write of same slots
#pragma unroll
  for (uint32_t y = 0; y < 32; ++y) lds[B1s ^ cswz(kxorB(L, 5, y))] = v[y];
  __syncthreads();
  // R2: dims 10..14; thread coords: dims 0..4 <- t bits 0..4, dims 5..9 <- t bits 5..9
  uint32_t B2 = 0u;
#pragma unroll
  for (int i = 0; i < 5; ++i) B2 ^= ((t >> i) & 1u) ? MK.M[L][i] : 0u;
#pragma unroll
  for (int i = 0; i < 5; ++i) B2 ^= ((t >> (5 + i)) & 1u) ? MK.M[L][5 + i] : 0u;
  const uint32_t B2s = cswz(B2);
#pragma unroll
  for (uint32_t y = 0; y < 32; ++y) v[y] = lds[B2s ^ cswz(kxorB(L, 10, y))];
#pragma unroll
  for (int j = 0; j < 5; ++j) {
    const float2 w = cs[10 + j];
    const float c = w.x, s = w.y;
    const float se = (__builtin_popcount(bb & MK.F[L][10 + j]) & 1) ? -s : s;
#pragma unroll
    for (uint32_t y = 0; y < 32; ++y) {
      if ((y >> j) & 1u) continue;
      const uint32_t y2 = y | (1u << j);
      const float a0 = v[y], a1 = v[y2];
      v[y]  = c * a0 - se * a1;
      v[y2] = c * a1 + se * a0;
    }
  }
  // merged store: pair (y, y^1) via M[L][10]; cls = bit0 of own address;
  // partner lane = t^1 (M[L][0]=e0). One unpredicated 64-lane dword store
  // per pair = full 128B-line coverage.
  {
    constexpr uint32_t rm = r2mask(L);
    const uint32_t cls = (uint32_t)__builtin_popcount(t & rm) & 1u;
    const uint32_t sb = bb ^ B2;
#pragma unroll
    for (uint32_t yp = 0; yp < 32; yp += 2) {
      const float p0 = __shfl_xor(v[yp], 1, 64);
      const float p1 = __shfl_xor(v[yp + 1], 1, 64);
      const uint32_t ad = (sb ^ kxorB(L, 10, yp) ^ (cls ? MK.M[L][10] : 0u)) & ~1u;
      const uint32_t val = cls ? pkh(p1, v[yp + 1]) : pkh(v[yp], p0);
      *(uint32_t*)(stateH + ad) = val;
    }
  }
}

template<int L>
__global__ __launch_bounds__(1024, 4) void kpassB(uint16_t* __restrict__ stateH,
                                                  const float* __restrict__ trig)
{
  __shared__ __align__(16) float lds[32768];   // 128 KiB (round-6 form)
  const uint32_t t = threadIdx.x;
  const uint32_t bb = (uint32_t)blockIdx.x << 15;
  // direct load: thread t owns 64 contiguous bytes (32 halves, tile order)
  float v[32];
  {
    const uint4* g4 = (const uint4*)(stateH + bb + (t << 5));
#pragma unroll
    for (uint32_t k = 0; k < 4; ++k) {
      const uint4 q = g4[k];
      float2 f;
      f = uph(q.x); v[8*k+0] = f.x; v[8*k+1] = f.y;
      f = uph(q.y); v[8*k+2] = f.x; v[8*k+3] = f.y;
      f = uph(q.z); v[8*k+4] = f.x; v[8*k+5] = f.y;
      f = uph(q.w); v[8*k+6] = f.x; v[8*k+7] = f.y;
    }
  }
  passB_tail<L>(v, lds, t, bb, trig, stateH);
}

// kinit: layer-0 product state built analytically in tile-address order
// (62 mults), then layer-1 passB tail. Write-only pass.
__global__ __launch_bounds__(1024, 4) void kinit(uint16_t* __restrict__ stateH,
                                                 const float* __restrict__ trig)
{
  __shared__ __align__(16) float lds[32768];
  const uint32_t t = threadIdx.x;
  const uint32_t bb = (uint32_t)blockIdx.x << 15;
  const float2* cs0 = (const float2*)trig;       // layer 0, indexed by bit
  const uint32_t hi = bb | (t << 5);
  float pt = 1.0f;
#pragma unroll
  for (int b = 5; b < 25; ++b) {
    const float2 w = cs0[b];
    pt *= ((hi >> b) & 1u) ? w.y : w.x;
  }
  float v[32];
  v[0] = pt;
#pragma unroll
  for (int j = 0; j < 5; ++j) {
    const float2 w = cs0[j];
#pragma unroll
    for (int o = 0; o < (1 << j); ++o) {
      v[o | (1 << j)] = v[o] * w.y;
      v[o]            = v[o] * w.x;
    }
  }
  passB_tail<1>(v, lds, t, bb, trig, stateH);
}

// ---- passA: pivots 15..24. Block = 32 contiguous spectators (slo) x 1024
// combos. Merged dword gathers/stores (lane-pairing, round-6 form); scalar
// fp16 LDS exchange (64 KiB -> 2 blocks/CU). Slot half-index layout:
// (combo20..24 << 10) | (combo15..19 << 5) | slo.
template<int L, bool FIN>
__global__ __launch_bounds__(1024, 4) void kpassA(uint16_t* __restrict__ stateH,
                                                  const float* __restrict__ trig,
                                                  float* __restrict__ outp)
{
  __shared__ __align__(16) uint16_t ldsH[32768];   // 64 KiB
  __shared__ float wsum[16];
  const uint32_t t = threadIdx.x;
  const uint32_t sbase = (uint32_t)blockIdx.x << 5;   // bits 5..14
  const float2* cs = (const float2*)(trig + 50 * L) + 15;
  const uint32_t slo = t & 31u;
  const uint32_t yf  = t >> 5;
  const uint32_t odd = t & 1u;
  // R0: register dims = pivots 15..19; yf -> pivots 20..24.
  uint32_t cy = 0u;
#pragma unroll
  for (int k = 0; k < 5; ++k) cy ^= ((yf >> k) & 1u) ? MK.M[L][20 + k] : 0u;
  const uint32_t A0 = sbase ^ slo ^ cy;
  float v[32];
  // merged gathers: pair (x, x^1) via M[L][15]; shfl_xor(1) redistributes.
#pragma unroll
  for (uint32_t xp = 0; xp < 32; xp += 2) {
    const uint32_t ax = (A0 ^ kxorB(L, 15, xp) ^ (odd ? MK.M[L][15] : 0u)) & ~1u;
    const uint32_t d  = *(const uint32_t*)(stateH + ax);
    const uint32_t dp = __shfl_xor(d, 1, 64);
    v[xp]     = h2fu(odd ? (dp >> 16) : d);
    v[xp + 1] = h2fu(odd ? (d >> 16)  : dp);
  }
#pragma unroll
  for (int j = 0; j < 5; ++j) {
    const float2 w = cs[j];
    const float c = w.x, s = w.y;
#pragma unroll
    for (uint32_t x = 0; x < 32; ++x) {
      if ((x >> j) & 1u) continue;
      const uint32_t x2 = x | (1u << j);
      const float a0 = v[x], a1 = v[x2];
      v[x]  = c * a0 - s * a1;
      v[x2] = s * a0 + c * a1;
    }
  }
  // exchange write: scalar fp16, slot (yf<<10)|(x<<5)|slo. Per instruction:
  // 2 dword-addresses per bank (yf 0/1) = free 2-way; sub-dword lane pairs
  // share a dword (byte-enabled writes).
  {
    const uint32_t wb = (yf << 10) + slo;
#pragma unroll
    for (uint32_t x = 0; x < 32; ++x) ldsH[wb + (x << 5)] = f2hs(v[x]);
  }
  __syncthreads();
  // R1: register dims = pivots 20..24; yf -> pivots 15..19.
  uint32_t cumt = 0u;
#pragma unroll
  for (int k = 0; k < 5; ++k) cumt ^= ((yf >> k) & 1u) ? MK.M[L][15 + k] : 0u;
  const uint32_t Ab = sbase ^ slo ^ cumt;
  {
    const uint32_t rb = (yf << 5) + slo;
#pragma unroll
    for (uint32_t x = 0; x < 32; ++x) v[x] = h2fs(ldsH[rb + (x << 10)]);
  }
#pragma unroll
  for (int j = 0; j < 5; ++j) {
    const float2 w = cs[5 + j];
    const float c = w.x, s = w.y;
#pragma unroll
    for (uint32_t x = 0; x < 32; ++x) {
      if ((x >> j) & 1u) continue;
      const uint32_t x2 = x | (1u << j);
      const float a0 = v[x], a1 = v[x2];
      v[x]  = c * a0 - s * a1;
      v[x2] = s * a0 + c * a1;
    }
  }
  if (!FIN) {
    // merged stores: pair (x, x^1) via M[L][20]; even lanes store x-dword,
    // odd lanes x^1-dword; one unpredicated 64-lane store per pair.
#pragma unroll
    for (uint32_t xp = 0; xp < 32; xp += 2) {
      const float p0 = __shfl_xor(v[xp], 1, 64);
      const float p1 = __shfl_xor(v[xp + 1], 1, 64);
      const uint32_t ad = (Ab ^ kxorB(L, 20, xp) ^ (odd ? MK.M[L][20] : 0u)) & ~1u;
      const uint32_t val = odd ? pkh(p1, v[xp + 1]) : pkh(v[xp], p0);
      *(uint32_t*)(stateH + ad) = val;
    }
  } else {
    constexpr uint32_t pz =
        (cpar(MK.M[L][20] & MK.fz) << 0) | (cpar(MK.M[L][21] & MK.fz) << 1) |
        (cpar(MK.M[L][22] & MK.fz) << 2) | (cpar(MK.M[L][23] & MK.fz) << 3) |
        (cpar(MK.M[L][24] & MK.fz) << 4);
    float acc = 0.0f;
#pragma unroll
    for (uint32_t x = 0; x < 32; ++x) {
      const float q = v[x] * v[x];
      acc += cpar(x & pz) ? -q : q;
    }
    if (__builtin_popcount(Ab & MK.fz) & 1) acc = -acc;
#pragma unroll
    for (int off = 32; off >= 1; off >>= 1) acc += __shfl_down(acc, off, 64);
    if ((t & 63u) == 0u) wsum[t >> 6] = acc;
    __syncthreads();
    if (t == 0) {
      float ssum = 0.0f;
#pragma unroll
      for (int w2 = 0; w2 < 16; ++w2) ssum += wsum[w2];
      atomicAdd(outp, ssum);
    }
  }
}

extern "C" void kernel_launch(void* const* d_in, const int* in_sizes, int n_in,
                              void* d_out, int out_size, void* d_ws, size_t ws_size,
                              hipStream_t stream)
{
  (void)in_sizes; (void)n_in; (void)out_size; (void)ws_size;
  const float* theta = (const float*)d_in[0];
  float* outp  = (float*)d_out;
  uint16_t* stateH = (uint16_t*)d_ws;                              // 2^25 halves
  float* trig  = (float*)((char*)d_ws + (size_t)(1u << 25) * 2u);  // 400 floats

  kprep<<<1, 256, 0, stream>>>(theta, trig, outp);
  kinit<<<1024, 1024, 0, stream>>>(stateH, trig);
  kpassA<1, false><<<1024, 1024, 0, stream>>>(stateH, trig, outp);
  kpassB<2><<<1024, 1024, 0, stream>>>(stateH, trig);
  kpassA<2, false><<<1024, 1024, 0, stream>>>(stateH, trig, outp);
  kpassB<3><<<1024, 1024, 0, stream>>>(stateH, trig);
  kpassA<3, false><<<1024, 1024, 0, stream>>>(stateH, trig, outp);
  kpassB<4><<<1024, 1024, 0, stream>>>(stateH, trig);
  kpassA<4, false><<<1024, 1024, 0, stream>>>(stateH, trig, outp);
  kpassB<5><<<1024, 1024, 0, stream>>>(stateH, trig);
  kpassA<5, false><<<1024, 1024, 0, stream>>>(stateH, trig, outp);
  kpassB<6><<<1024, 1024, 0, stream>>>(stateH, trig);
  kpassA<6, false><<<1024, 1024, 0, stream>>>(stateH, trig, outp);
  kpassB<7><<<1024, 1024, 0, stream>>>(stateH, trig);
  kpassA<7, true><<<1024, 1024, 0, stream>>>(stateH, trig, outp);
}

// Round 10
// 600.444 us; speedup vs baseline: 1.6972x; 1.1340x over previous
//
#include <hip/hip_runtime.h>
#include <hip/hip_fp16.h>
#include <stdint.h>

// 25-qubit, 8-layer RY + CNOT-chain circuit, output <Z_q0>.
// CNOT chains deferred into a GF(2) change-of-basis; only 200 RYs touch the
// state (2^25 fp16 = 64 MiB in d_ws). Arithmetic in f32.
// Round 10: rotations rewritten as packed FP32 (float2 ext-vectors ->
// v_pk_mul_f32/v_pk_fma_f32, the only path to the 157 TF vector rate).
// Working set = v2f q[16], pack dim = element/register bit 0. Uniform
// update new_e = c*e + sigma(e)*se*partner(e) (sigma = +-1 compile-time)
// removes base/partner asymmetry; pack-crossing dims use component swap
// (op_sel) with sign-mixed {-se,+se}. Memory/LDS patterns identical to
// round 9 (best: 680.9 us; kpassB VALU-bound at 62%).

#define NQ 25
#define DEPTH 8

typedef float v2f __attribute__((ext_vector_type(2)));

struct MaskSet {
  uint32_t M[DEPTH][NQ];   // M[l][b] = column b of W_l (pairing masks)
  uint32_t F[DEPTH][NQ];   // F[l][b] = row b of W_l^-1 (orientation functionals)
  uint32_t fz;             // final Z functional (row 24 of W_8^-1)
};

__host__ __device__ constexpr MaskSet buildMasks() {
  MaskSet r{};
  uint32_t col[NQ] = {}, inv[NQ] = {};
  for (int j = 0; j < NQ; ++j) { col[j] = 1u << j; inv[j] = 1u << j; }
  for (int l = 0; l < DEPTH; ++l) {
    for (int b = 0; b < NQ; ++b) { r.M[l][b] = col[b]; r.F[l][b] = inv[b]; }
    for (int w = 0; w < NQ - 1; ++w) {   // CNOT chain of layer l
      const int cb = 24 - w, tb = 23 - w;
      col[cb] ^= col[tb];
      inv[tb] ^= inv[cb];
    }
  }
  r.fz = inv[24];
  return r;
}

constexpr MaskSet MK = buildMasks();

// f32 LDS swizzle for kpassB (2^15 floats = 128 KiB): XOR slot bits 2..4
// with owner bits 5..7. Preserves 16B groups -> b128-friendly.
__host__ __device__ constexpr uint32_t cswz(uint32_t a) { return a ^ ((a >> 3) & 28u); }

__host__ __device__ constexpr uint32_t kxorB(int L, int d0, uint32_t y) {
  uint32_t a = 0;
  for (int i = 0; i < 5; ++i) if ((y >> i) & 1u) a ^= MK.M[L][d0 + i];
  return a;
}

__host__ __device__ constexpr uint32_t cpar(uint32_t x) {
  uint32_t p = 0;
  for (int i = 0; i < 32; ++i) p ^= (x >> i) & 1u;
  return p;
}

// Evenness functional for R2's low-bit: bit0 of B2(t) = parity(t & r2mask(L)).
__host__ __device__ constexpr uint32_t r2mask(int L) {
  uint32_t r = 0;
  for (int i = 0; i < 5; ++i) {
    r |= (MK.M[L][i] & 1u) << i;           // t bits 0..4 -> dims 0..4
    r |= (MK.M[L][5 + i] & 1u) << (5 + i); // t bits 5..9 -> dims 5..9
  }
  return r;
}

__device__ __forceinline__ v2f vswap(v2f x) { return __builtin_shufflevector(x, x, 1, 0); }
__device__ __forceinline__ v2f vfma(v2f a, v2f b, v2f c) { return __builtin_elementwise_fma(a, b, c); }

__device__ __forceinline__ uint32_t pkh(float a, float b) {
  __half2 h = __floats2half2_rn(a, b);   // round-to-nearest (unbiased)
  return __builtin_bit_cast(uint32_t, h);
}
__device__ __forceinline__ v2f uphv(uint32_t w) {
  __half2 h = __builtin_bit_cast(__half2, w);
  float2 f = __half22float2(h);
  return (v2f){ f.x, f.y };
}
__device__ __forceinline__ float h2fu(uint32_t x) {   // low 16 bits -> f32
  __half h = __builtin_bit_cast(__half, (uint16_t)(x & 0xffffu));
  return __half2float(h);
}
__device__ __forceinline__ float h2fs(uint16_t x) {
  __half h = __builtin_bit_cast(__half, x);
  return __half2float(h);
}
__device__ __forceinline__ uint16_t f2hs(float x) {
  __half h = __float2half_rn(x);
  return __builtin_bit_cast(uint16_t, h);
}

__global__ void kprep(const float* __restrict__ theta, float* __restrict__ trig,
                      float* __restrict__ outp)
{
  int t = threadIdx.x;
  if (t == 0) outp[0] = 0.0f;
  if (t < 200) {
    int l = t / 25, b = t % 25;            // b = bit position, qubit w = 24-b
    float th = theta[l * 25 + (24 - b)] * 0.5f;
    trig[2 * t]     = cosf(th);
    trig[2 * t + 1] = sinf(th);
  }
}

// Packed rotation for register-space dims (mask = 1<<j in register index,
// pack = register bit 0): uniform se, sigma(e) = bit j of e.
template<int JLO>
__device__ __forceinline__ void rot_pow2(v2f (&q)[16], const float2* cs,
                                         const float* se5)
{
#pragma unroll
  for (int j = 0; j < 5; ++j) {
    const float c = cs[JLO + j].x;
    const float se = se5[j];
    const v2f c2 = { c, c };
    if (j == 0) {
      const v2f sv = { -se, se };
#pragma unroll
      for (uint32_t g = 0; g < 16; ++g)
        q[g] = vfma(sv, vswap(q[g]), c2 * q[g]);
    } else {
      const v2f sP = { se, se }, sM = { -se, -se };
      const uint32_t mh = 1u << (j - 1);
#pragma unroll
      for (uint32_t g = 0; g < 16; ++g) {
        const uint32_t h = g ^ mh;
        if (h < g) continue;
        const v2f a = q[g], b = q[h];
        q[g] = vfma(sM, b, c2 * a);
        q[h] = vfma(sP, a, c2 * b);
      }
    }
  }
}

// ---- passB tail: R0 (general 5-bit masks) -> f32 LDS -> R1 -> writeback ->
//      R2 -> merged full-wave fp16 dword stores.
template<int L>
__device__ __forceinline__ void passB_tail(v2f (&q)[16], float* lds,
                                           const uint32_t t, const uint32_t bb,
                                           const float* __restrict__ trig,
                                           uint16_t* __restrict__ stateH)
{
  const float2* cs = (const float2*)(trig + 50 * L);
  // R0: dims 0..4, masks M[L][j]&31 (general), sigma(e) = parity(e & fj5).
#pragma unroll
  for (int j = 0; j < 5; ++j) {
    const float2 w = cs[j];
    const float c = w.x, s = w.y;
    const float se = (__builtin_popcount((bb | (t << 5)) & MK.F[L][j]) & 1) ? -s : s;
    const uint32_t mmj = MK.M[L][j] & 31u;
    const uint32_t fj5 = MK.F[L][j] & 31u;
    const uint32_t mh = mmj >> 1;
    const bool sw = (mmj & 1u) != 0u;
    const v2f c2 = { c, c };
    const v2f sOdd = (fj5 & 1u) ? (v2f){ se, -se } : (v2f){ se, se };
    const v2f sEvn = (fj5 & 1u) ? (v2f){ -se, se } : (v2f){ -se, -se };
#pragma unroll
    for (uint32_t g = 0; g < 16; ++g) {
      const uint32_t h = g ^ mh;
      if (h < g) continue;
      const v2f a = q[g], b = q[h];
      const v2f pa = sw ? vswap(b) : b;
      const v2f sa = (__builtin_popcount(g & (fj5 >> 1)) & 1) ? sOdd : sEvn;
      q[g] = vfma(sa, pa, c2 * a);
      if (h != g) {
        const v2f pb = sw ? vswap(a) : a;
        const v2f sb2 = (__builtin_popcount(h & (fj5 >> 1)) & 1) ? sOdd : sEvn;
        q[h] = vfma(sb2, pb, c2 * b);
      }
    }
  }
  // exchange 1: write own segment (b128, cswz layout, f32)
  {
    float4* l4 = (float4*)lds;
#pragma unroll
    for (uint32_t k = 0; k < 8; ++k) {
      float4 f4 = { q[2*k].x, q[2*k].y, q[2*k+1].x, q[2*k+1].y };
      l4[cswz((t << 5) + 4u * k) >> 2] = f4;
    }
  }
  __syncthreads();
  // R1: dims 5..9; thread coords: dims 0..4 <- t bits 0..4, dims 10..14 <- t bits 5..9
  uint32_t B1 = 0u;
#pragma unroll
  for (int i = 0; i < 5; ++i) B1 ^= ((t >> i) & 1u) ? MK.M[L][i] : 0u;
#pragma unroll
  for (int i = 0; i < 5; ++i) B1 ^= ((t >> (5 + i)) & 1u) ? MK.M[L][10 + i] : 0u;
  const uint32_t B1s = cswz(B1);
#pragma unroll
  for (uint32_t g = 0; g < 16; ++g) {
    q[g].x = lds[B1s ^ cswz(kxorB(L, 5, 2*g))];
    q[g].y = lds[B1s ^ cswz(kxorB(L, 5, 2*g+1))];
  }
  {
    float se5[5];
#pragma unroll
    for (int j = 0; j < 5; ++j) {
      const float s = cs[5 + j].y;
      se5[j] = (__builtin_popcount(bb & MK.F[L][5 + j]) & 1) ? -s : s;
    }
    rot_pow2<5>(q, cs, se5);
  }
  __syncthreads();   // protect re-write of same slots
#pragma unroll
  for (uint32_t g = 0; g < 16; ++g) {
    lds[B1s ^ cswz(kxorB(L, 5, 2*g))]   = q[g].x;
    lds[B1s ^ cswz(kxorB(L, 5, 2*g+1))] = q[g].y;
  }
  __syncthreads();
  // R2: dims 10..14; thread coords: dims 0..4 <- t bits 0..4, dims 5..9 <- t bits 5..9
  uint32_t B2 = 0u;
#pragma unroll
  for (int i = 0; i < 5; ++i) B2 ^= ((t >> i) & 1u) ? MK.M[L][i] : 0u;
#pragma unroll
  for (int i = 0; i < 5; ++i) B2 ^= ((t >> (5 + i)) & 1u) ? MK.M[L][5 + i] : 0u;
  const uint32_t B2s = cswz(B2);
#pragma unroll
  for (uint32_t g = 0; g < 16; ++g) {
    q[g].x = lds[B2s ^ cswz(kxorB(L, 10, 2*g))];
    q[g].y = lds[B2s ^ cswz(kxorB(L, 10, 2*g+1))];
  }
  {
    float se5[5];
#pragma unroll
    for (int j = 0; j < 5; ++j) {
      const float s = cs[10 + j].y;
      se5[j] = (__builtin_popcount(bb & MK.F[L][10 + j]) & 1) ? -s : s;
    }
    rot_pow2<10>(q, cs, se5);
  }
  // merged store: pair (y, y^1) via M[L][10]; cls = bit0 of own address;
  // partner lane = t^1 (M[L][0]=e0). One unpredicated 64-lane dword store
  // per pair = full 128B-line coverage.
  {
    constexpr uint32_t rm = r2mask(L);
    const uint32_t cls = (uint32_t)__builtin_popcount(t & rm) & 1u;
    const uint32_t sb = bb ^ B2;
#pragma unroll
    for (uint32_t g = 0; g < 16; ++g) {
      const float p0 = __shfl_xor(q[g].x, 1, 64);
      const float p1 = __shfl_xor(q[g].y, 1, 64);
      const uint32_t ad = (sb ^ kxorB(L, 10, 2*g) ^ (cls ? MK.M[L][10] : 0u)) & ~1u;
      const uint32_t val = cls ? pkh(p1, q[g].y) : pkh(q[g].x, p0);
      *(uint32_t*)(stateH + ad) = val;
    }
  }
}

template<int L>
__global__ __launch_bounds__(1024, 4) void kpassB(uint16_t* __restrict__ stateH,
                                                  const float* __restrict__ trig)
{
  __shared__ __align__(16) float lds[32768];   // 128 KiB
  const uint32_t t = threadIdx.x;
  const uint32_t bb = (uint32_t)blockIdx.x << 15;
  // direct load: thread t owns 64 contiguous bytes (32 halves, tile order)
  v2f q[16];
  {
    const uint4* g4 = (const uint4*)(stateH + bb + (t << 5));
#pragma unroll
    for (uint32_t k = 0; k < 4; ++k) {
      const uint4 d = g4[k];
      q[4*k+0] = uphv(d.x); q[4*k+1] = uphv(d.y);
      q[4*k+2] = uphv(d.z); q[4*k+3] = uphv(d.w);
    }
  }
  passB_tail<L>(q, lds, t, bb, trig, stateH);
}

// kinit: layer-0 product state built analytically in tile-address order
// (packed doubling tree), then layer-1 passB tail. Write-only pass.
__global__ __launch_bounds__(1024, 4) void kinit(uint16_t* __restrict__ stateH,
                                                 const float* __restrict__ trig)
{
  __shared__ __align__(16) float lds[32768];
  const uint32_t t = threadIdx.x;
  const uint32_t bb = (uint32_t)blockIdx.x << 15;
  const float2* cs0 = (const float2*)trig;       // layer 0, indexed by bit
  const uint32_t hi = bb | (t << 5);
  float pt = 1.0f;
#pragma unroll
  for (int b = 5; b < 25; ++b) {
    const float2 w = cs0[b];
    pt *= ((hi >> b) & 1u) ? w.y : w.x;
  }
  v2f q[16];
  {
    const float2 w0 = cs0[0];
    q[0] = (v2f){ pt * w0.x, pt * w0.y };
#pragma unroll
    for (int j = 1; j < 5; ++j) {
      const float2 w = cs0[j];
      const v2f wx = { w.x, w.x }, wy = { w.y, w.y };
#pragma unroll
      for (int g = 0; g < (1 << (j - 1)); ++g) {
        q[g | (1 << (j - 1))] = q[g] * wy;
        q[g] = q[g] * wx;
      }
    }
  }
  passB_tail<1>(q, lds, t, bb, trig, stateH);
}

// ---- passA: pivots 15..24. Block = 32 contiguous spectators (slo) x 1024
// combos. Merged dword gathers/stores (lane-pairing); scalar fp16 LDS
// exchange (64 KiB -> 2 blocks/CU); packed rotations (se = +s uniform).
template<int L, bool FIN>
__global__ __launch_bounds__(1024, 4) void kpassA(uint16_t* __restrict__ stateH,
                                                  const float* __restrict__ trig,
                                                  float* __restrict__ outp)
{
  __shared__ __align__(16) uint16_t ldsH[32768];   // 64 KiB
  __shared__ float wsum[16];
  const uint32_t t = threadIdx.x;
  const uint32_t sbase = (uint32_t)blockIdx.x << 5;   // bits 5..14
  const float2* cs = (const float2*)(trig + 50 * L) + 15;
  const uint32_t slo = t & 31u;
  const uint32_t yf  = t >> 5;
  const uint32_t odd = t & 1u;
  // R0: register dims = pivots 15..19; yf -> pivots 20..24.
  uint32_t cy = 0u;
#pragma unroll
  for (int k = 0; k < 5; ++k) cy ^= ((yf >> k) & 1u) ? MK.M[L][20 + k] : 0u;
  const uint32_t A0 = sbase ^ slo ^ cy;
  v2f q[16];
  // merged gathers: pair (x, x^1) via M[L][15]; shfl_xor(1) redistributes.
#pragma unroll
  for (uint32_t g = 0; g < 16; ++g) {
    const uint32_t ax = (A0 ^ kxorB(L, 15, 2*g) ^ (odd ? MK.M[L][15] : 0u)) & ~1u;
    const uint32_t d  = *(const uint32_t*)(stateH + ax);
    const uint32_t dp = __shfl_xor(d, 1, 64);
    q[g].x = h2fu(odd ? (dp >> 16) : d);
    q[g].y = h2fu(odd ? (d >> 16)  : dp);
  }
  {
    float se5[5];
#pragma unroll
    for (int j = 0; j < 5; ++j) se5[j] = cs[j].y;
    rot_pow2<0>(q, cs, se5);
  }
  // exchange write: scalar fp16, slot (yf<<10)|(x<<5)|slo.
  {
    const uint32_t wb = (yf << 10) + slo;
#pragma unroll
    for (uint32_t g = 0; g < 16; ++g) {
      ldsH[wb + ((2*g) << 5)]   = f2hs(q[g].x);
      ldsH[wb + ((2*g+1) << 5)] = f2hs(q[g].y);
    }
  }
  __syncthreads();
  // R1: register dims = pivots 20..24; yf -> pivots 15..19.
  uint32_t cumt = 0u;
#pragma unroll
  for (int k = 0; k < 5; ++k) cumt ^= ((yf >> k) & 1u) ? MK.M[L][15 + k] : 0u;
  const uint32_t Ab = sbase ^ slo ^ cumt;
  {
    const uint32_t rb = (yf << 5) + slo;
#pragma unroll
    for (uint32_t g = 0; g < 16; ++g) {
      q[g].x = h2fs(ldsH[rb + ((2*g) << 10)]);
      q[g].y = h2fs(ldsH[rb + ((2*g+1) << 10)]);
    }
  }
  {
    float se5[5];
#pragma unroll
    for (int j = 0; j < 5; ++j) se5[j] = cs[5 + j].y;
    rot_pow2<5>(q, cs, se5);
  }
  if (!FIN) {
    // merged stores: pair (x, x^1) via M[L][20]; even lanes store x-dword,
    // odd lanes x^1-dword; one unpredicated 64-lane store per pair.
#pragma unroll
    for (uint32_t g = 0; g < 16; ++g) {
      const float p0 = __shfl_xor(q[g].x, 1, 64);
      const float p1 = __shfl_xor(q[g].y, 1, 64);
      const uint32_t ad = (Ab ^ kxorB(L, 20, 2*g) ^ (odd ? MK.M[L][20] : 0u)) & ~1u;
      const uint32_t val = odd ? pkh(p1, q[g].y) : pkh(q[g].x, p0);
      *(uint32_t*)(stateH + ad) = val;
    }
  } else {
    constexpr uint32_t pz =
        (cpar(MK.M[L][20] & MK.fz) << 0) | (cpar(MK.M[L][21] & MK.fz) << 1) |
        (cpar(MK.M[L][22] & MK.fz) << 2) | (cpar(MK.M[L][23] & MK.fz) << 3) |
        (cpar(MK.M[L][24] & MK.fz) << 4);
    float acc = 0.0f;
#pragma unroll
    for (uint32_t g = 0; g < 16; ++g) {
      const v2f sq = q[g] * q[g];
      acc += cpar((2*g) & pz)   ? -sq.x : sq.x;
      acc += cpar((2*g+1) & pz) ? -sq.y : sq.y;
    }
    if (__builtin_popcount(Ab & MK.fz) & 1) acc = -acc;
#pragma unroll
    for (int off = 32; off >= 1; off >>= 1) acc += __shfl_down(acc, off, 64);
    if ((t & 63u) == 0u) wsum[t >> 6] = acc;
    __syncthreads();
    if (t == 0) {
      float ssum = 0.0f;
#pragma unroll
      for (int w2 = 0; w2 < 16; ++w2) ssum += wsum[w2];
      atomicAdd(outp, ssum);
    }
  }
}

extern "C" void kernel_launch(void* const* d_in, const int* in_sizes, int n_in,
                              void* d_out, int out_size, void* d_ws, size_t ws_size,
                              hipStream_t stream)
{
  (void)in_sizes; (void)n_in; (void)out_size; (void)ws_size;
  const float* theta = (const float*)d_in[0];
  float* outp  = (float*)d_out;
  uint16_t* stateH = (uint16_t*)d_ws;                              // 2^25 halves
  float* trig  = (float*)((char*)d_ws + (size_t)(1u << 25) * 2u);  // 400 floats

  kprep<<<1, 256, 0, stream>>>(theta, trig, outp);
  kinit<<<1024, 1024, 0, stream>>>(stateH, trig);
  kpassA<1, false><<<1024, 1024, 0, stream>>>(stateH, trig, outp);
  kpassB<2><<<1024, 1024, 0, stream>>>(stateH, trig);
  kpassA<2, false><<<1024, 1024, 0, stream>>>(stateH, trig, outp);
  kpassB<3><<<1024, 1024, 0, stream>>>(stateH, trig);
  kpassA<3, false><<<1024, 1024, 0, stream>>>(stateH, trig, outp);
  kpassB<4><<<1024, 1024, 0, stream>>>(stateH, trig);
  kpassA<4, false><<<1024, 1024, 0, stream>>>(stateH, trig, outp);
  kpassB<5><<<1024, 1024, 0, stream>>>(stateH, trig);
  kpassA<5, false><<<1024, 1024, 0, stream>>>(stateH, trig, outp);
  kpassB<6><<<1024, 1024, 0, stream>>>(stateH, trig);
  kpassA<6, false><<<1024, 1024, 0, stream>>>(stateH, trig, outp);
  kpassB<7><<<1024, 1024, 0, stream>>>(stateH, trig);
  kpassA<7, true><<<1024, 1024, 0, stream>>>(stateH, trig, outp);
}

// Round 11
// 594.973 us; speedup vs baseline: 1.7128x; 1.0092x over previous
//
#include <hip/hip_runtime.h>
#include <hip/hip_fp16.h>
#include <stdint.h>

// 25-qubit, 8-layer RY + CNOT-chain circuit, output <Z_q0>.
// CNOT chains deferred into a GF(2) change-of-basis; only 200 RYs touch the
// state (2^25 fp16 = 64 MiB in d_ws). Arithmetic in f32, packed (v_pk_*).
// Round 11: kpassB/kinit LDS exchange in fp16 (2^15 halves = 64 KiB -> 2
// blocks/CU co-residency; round-7 idea, which failed only due to the
// (1024,8) register collapse, not the LDS change). (1024,4) bounds; the
// backend targets 64 VGPRs from the LDS-implied occupancy and the packed
// kernel needs ~52 -> clean fit (round-9 kpassA precedent). Also drops the
// pre-writeback barrier (R1 slot->thread map is bijective; each thread
// writes back exactly what it read — validated in round 7): 3 -> 2 barriers.

#define NQ 25
#define DEPTH 8

typedef float v2f __attribute__((ext_vector_type(2)));

struct MaskSet {
  uint32_t M[DEPTH][NQ];   // M[l][b] = column b of W_l (pairing masks)
  uint32_t F[DEPTH][NQ];   // F[l][b] = row b of W_l^-1 (orientation functionals)
  uint32_t fz;             // final Z functional (row 24 of W_8^-1)
};

__host__ __device__ constexpr MaskSet buildMasks() {
  MaskSet r{};
  uint32_t col[NQ] = {}, inv[NQ] = {};
  for (int j = 0; j < NQ; ++j) { col[j] = 1u << j; inv[j] = 1u << j; }
  for (int l = 0; l < DEPTH; ++l) {
    for (int b = 0; b < NQ; ++b) { r.M[l][b] = col[b]; r.F[l][b] = inv[b]; }
    for (int w = 0; w < NQ - 1; ++w) {   // CNOT chain of layer l
      const int cb = 24 - w, tb = 23 - w;
      col[cb] ^= col[tb];
      inv[tb] ^= inv[cb];
    }
  }
  r.fz = inv[24];
  return r;
}

constexpr MaskSet MK = buildMasks();

// Half-index swizzle for 2^15-half LDS: XOR bits 3..5 with bits 6..8.
// Linear over GF(2); preserves 8-half (16B) groups -> b128-friendly.
// Round 7 measured 0 bank conflicts with this layout.
__host__ __device__ constexpr uint32_t hswz(uint32_t h) { return h ^ ((h >> 3) & 0x38u); }

__host__ __device__ constexpr uint32_t kxorB(int L, int d0, uint32_t y) {
  uint32_t a = 0;
  for (int i = 0; i < 5; ++i) if ((y >> i) & 1u) a ^= MK.M[L][d0 + i];
  return a;
}

__host__ __device__ constexpr uint32_t cpar(uint32_t x) {
  uint32_t p = 0;
  for (int i = 0; i < 32; ++i) p ^= (x >> i) & 1u;
  return p;
}

// Evenness functional for R2's low-bit: bit0 of B2(t) = parity(t & r2mask(L)).
__host__ __device__ constexpr uint32_t r2mask(int L) {
  uint32_t r = 0;
  for (int i = 0; i < 5; ++i) {
    r |= (MK.M[L][i] & 1u) << i;           // t bits 0..4 -> dims 0..4
    r |= (MK.M[L][5 + i] & 1u) << (5 + i); // t bits 5..9 -> dims 5..9
  }
  return r;
}

__device__ __forceinline__ v2f vswap(v2f x) { return __builtin_shufflevector(x, x, 1, 0); }
__device__ __forceinline__ v2f vfma(v2f a, v2f b, v2f c) { return __builtin_elementwise_fma(a, b, c); }

__device__ __forceinline__ uint32_t pkh(float a, float b) {
  __half2 h = __floats2half2_rn(a, b);   // round-to-nearest (unbiased)
  return __builtin_bit_cast(uint32_t, h);
}
__device__ __forceinline__ uint32_t pkhv(v2f q) { return pkh(q.x, q.y); }
__device__ __forceinline__ v2f uphv(uint32_t w) {
  __half2 h = __builtin_bit_cast(__half2, w);
  float2 f = __half22float2(h);
  return (v2f){ f.x, f.y };
}
__device__ __forceinline__ float h2fu(uint32_t x) {   // low 16 bits -> f32
  __half h = __builtin_bit_cast(__half, (uint16_t)(x & 0xffffu));
  return __half2float(h);
}
__device__ __forceinline__ float h2fs(uint16_t x) {
  __half h = __builtin_bit_cast(__half, x);
  return __half2float(h);
}
__device__ __forceinline__ uint16_t f2hs(float x) {
  __half h = __float2half_rn(x);
  return __builtin_bit_cast(uint16_t, h);
}

__global__ void kprep(const float* __restrict__ theta, float* __restrict__ trig,
                      float* __restrict__ outp)
{
  int t = threadIdx.x;
  if (t == 0) outp[0] = 0.0f;
  if (t < 200) {
    int l = t / 25, b = t % 25;            // b = bit position, qubit w = 24-b
    float th = theta[l * 25 + (24 - b)] * 0.5f;
    trig[2 * t]     = cosf(th);
    trig[2 * t + 1] = sinf(th);
  }
}

// Packed rotation for register-space dims (mask = 1<<j in register index,
// pack = register bit 0): uniform se, sigma(e) = bit j of e.
template<int JLO>
__device__ __forceinline__ void rot_pow2(v2f (&q)[16], const float2* cs,
                                         const float* se5)
{
#pragma unroll
  for (int j = 0; j < 5; ++j) {
    const float c = cs[JLO + j].x;
    const float se = se5[j];
    const v2f c2 = { c, c };
    if (j == 0) {
      const v2f sv = { -se, se };
#pragma unroll
      for (uint32_t g = 0; g < 16; ++g)
        q[g] = vfma(sv, vswap(q[g]), c2 * q[g]);
    } else {
      const v2f sP = { se, se }, sM = { -se, -se };
      const uint32_t mh = 1u << (j - 1);
#pragma unroll
      for (uint32_t g = 0; g < 16; ++g) {
        const uint32_t h = g ^ mh;
        if (h < g) continue;
        const v2f a = q[g], b = q[h];
        q[g] = vfma(sM, b, c2 * a);
        q[h] = vfma(sP, a, c2 * b);
      }
    }
  }
}

// ---- passB tail: R0 (general 5-bit masks) -> fp16 LDS (b128 write) -> R1
//      (scalar u16 reads) -> writeback (no pre-barrier; bijective slots) ->
//      R2 -> merged full-wave fp16 dword stores. 2 barriers total.
template<int L>
__device__ __forceinline__ void passB_tail(v2f (&q)[16], uint16_t* ldsH,
                                           const uint32_t t, const uint32_t bb,
                                           const float* __restrict__ trig,
                                           uint16_t* __restrict__ stateH)
{
  const float2* cs = (const float2*)(trig + 50 * L);
  // R0: dims 0..4, masks M[L][j]&31 (general), sigma(e) = parity(e & fj5).
#pragma unroll
  for (int j = 0; j < 5; ++j) {
    const float2 w = cs[j];
    const float c = w.x, s = w.y;
    const float se = (__builtin_popcount((bb | (t << 5)) & MK.F[L][j]) & 1) ? -s : s;
    const uint32_t mmj = MK.M[L][j] & 31u;
    const uint32_t fj5 = MK.F[L][j] & 31u;
    const uint32_t mh = mmj >> 1;
    const bool sw = (mmj & 1u) != 0u;
    const v2f c2 = { c, c };
    const v2f sOdd = (fj5 & 1u) ? (v2f){ se, -se } : (v2f){ se, se };
    const v2f sEvn = (fj5 & 1u) ? (v2f){ -se, se } : (v2f){ -se, -se };
#pragma unroll
    for (uint32_t g = 0; g < 16; ++g) {
      const uint32_t h = g ^ mh;
      if (h < g) continue;
      const v2f a = q[g], b = q[h];
      const v2f pa = sw ? vswap(b) : b;
      const v2f sa = (__builtin_popcount(g & (fj5 >> 1)) & 1) ? sOdd : sEvn;
      q[g] = vfma(sa, pa, c2 * a);
      if (h != g) {
        const v2f pb = sw ? vswap(a) : a;
        const v2f sb2 = (__builtin_popcount(h & (fj5 >> 1)) & 1) ? sOdd : sEvn;
        q[h] = vfma(sb2, pb, c2 * b);
      }
    }
  }
  // exchange 1: own segment, 8 halves per b128 (hswz layout), 4 insts
  {
    uint4* l4 = (uint4*)ldsH;
#pragma unroll
    for (uint32_t k = 0; k < 4; ++k) {
      uint4 d = { pkhv(q[4*k+0]), pkhv(q[4*k+1]), pkhv(q[4*k+2]), pkhv(q[4*k+3]) };
      l4[hswz((t << 5) + 8u * k) >> 3] = d;
    }
  }
  __syncthreads();
  // R1: dims 5..9; thread coords: dims 0..4 <- t bits 0..4, dims 10..14 <- t bits 5..9
  uint32_t B1 = 0u;
#pragma unroll
  for (int i = 0; i < 5; ++i) B1 ^= ((t >> i) & 1u) ? MK.M[L][i] : 0u;
#pragma unroll
  for (int i = 0; i < 5; ++i) B1 ^= ((t >> (5 + i)) & 1u) ? MK.M[L][10 + i] : 0u;
  const uint32_t B1s = hswz(B1);
#pragma unroll
  for (uint32_t g = 0; g < 16; ++g) {
    q[g].x = h2fs(ldsH[B1s ^ hswz(kxorB(L, 5, 2*g))]);
    q[g].y = h2fs(ldsH[B1s ^ hswz(kxorB(L, 5, 2*g+1))]);
  }
  {
    float se5[5];
#pragma unroll
    for (int j = 0; j < 5; ++j) {
      const float s = cs[5 + j].y;
      se5[j] = (__builtin_popcount(bb & MK.F[L][5 + j]) & 1) ? -s : s;
    }
    rot_pow2<5>(q, cs, se5);
  }
  // writeback to own read slots — no barrier needed before (slot->thread map
  // is bijective; each thread writes exactly what it read)
#pragma unroll
  for (uint32_t g = 0; g < 16; ++g) {
    ldsH[B1s ^ hswz(kxorB(L, 5, 2*g))]   = f2hs(q[g].x);
    ldsH[B1s ^ hswz(kxorB(L, 5, 2*g+1))] = f2hs(q[g].y);
  }
  __syncthreads();
  // R2: dims 10..14; thread coords: dims 0..4 <- t bits 0..4, dims 5..9 <- t bits 5..9
  uint32_t B2 = 0u;
#pragma unroll
  for (int i = 0; i < 5; ++i) B2 ^= ((t >> i) & 1u) ? MK.M[L][i] : 0u;
#pragma unroll
  for (int i = 0; i < 5; ++i) B2 ^= ((t >> (5 + i)) & 1u) ? MK.M[L][5 + i] : 0u;
  const uint32_t B2s = hswz(B2);
#pragma unroll
  for (uint32_t g = 0; g < 16; ++g) {
    q[g].x = h2fs(ldsH[B2s ^ hswz(kxorB(L, 10, 2*g))]);
    q[g].y = h2fs(ldsH[B2s ^ hswz(kxorB(L, 10, 2*g+1))]);
  }
  {
    float se5[5];
#pragma unroll
    for (int j = 0; j < 5; ++j) {
      const float s = cs[10 + j].y;
      se5[j] = (__builtin_popcount(bb & MK.F[L][10 + j]) & 1) ? -s : s;
    }
    rot_pow2<10>(q, cs, se5);
  }
  // merged store: pair (y, y^1) via M[L][10]; cls = bit0 of own address;
  // partner lane = t^1 (M[L][0]=e0). One unpredicated 64-lane dword store
  // per pair = full 128B-line coverage.
  {
    constexpr uint32_t rm = r2mask(L);
    const uint32_t cls = (uint32_t)__builtin_popcount(t & rm) & 1u;
    const uint32_t sb = bb ^ B2;
#pragma unroll
    for (uint32_t g = 0; g < 16; ++g) {
      const float p0 = __shfl_xor(q[g].x, 1, 64);
      const float p1 = __shfl_xor(q[g].y, 1, 64);
      const uint32_t ad = (sb ^ kxorB(L, 10, 2*g) ^ (cls ? MK.M[L][10] : 0u)) & ~1u;
      const uint32_t val = cls ? pkh(p1, q[g].y) : pkh(q[g].x, p0);
      *(uint32_t*)(stateH + ad) = val;
    }
  }
}

template<int L>
__global__ __launch_bounds__(1024, 4) void kpassB(uint16_t* __restrict__ stateH,
                                                  const float* __restrict__ trig)
{
  __shared__ __align__(16) uint16_t ldsH[32768];   // 64 KiB -> 2 blocks/CU
  const uint32_t t = threadIdx.x;
  const uint32_t bb = (uint32_t)blockIdx.x << 15;
  // direct load: thread t owns 64 contiguous bytes (32 halves, tile order)
  v2f q[16];
  {
    const uint4* g4 = (const uint4*)(stateH + bb + (t << 5));
#pragma unroll
    for (uint32_t k = 0; k < 4; ++k) {
      const uint4 d = g4[k];
      q[4*k+0] = uphv(d.x); q[4*k+1] = uphv(d.y);
      q[4*k+2] = uphv(d.z); q[4*k+3] = uphv(d.w);
    }
  }
  passB_tail<L>(q, ldsH, t, bb, trig, stateH);
}

// kinit: layer-0 product state built analytically in tile-address order
// (packed doubling tree), then layer-1 passB tail. Write-only pass.
__global__ __launch_bounds__(1024, 4) void kinit(uint16_t* __restrict__ stateH,
                                                 const float* __restrict__ trig)
{
  __shared__ __align__(16) uint16_t ldsH[32768];
  const uint32_t t = threadIdx.x;
  const uint32_t bb = (uint32_t)blockIdx.x << 15;
  const float2* cs0 = (const float2*)trig;       // layer 0, indexed by bit
  const uint32_t hi = bb | (t << 5);
  float pt = 1.0f;
#pragma unroll
  for (int b = 5; b < 25; ++b) {
    const float2 w = cs0[b];
    pt *= ((hi >> b) & 1u) ? w.y : w.x;
  }
  v2f q[16];
  {
    const float2 w0 = cs0[0];
    q[0] = (v2f){ pt * w0.x, pt * w0.y };
#pragma unroll
    for (int j = 1; j < 5; ++j) {
      const float2 w = cs0[j];
      const v2f wx = { w.x, w.x }, wy = { w.y, w.y };
#pragma unroll
      for (int g = 0; g < (1 << (j - 1)); ++g) {
        q[g | (1 << (j - 1))] = q[g] * wy;
        q[g] = q[g] * wx;
      }
    }
  }
  passB_tail<1>(q, ldsH, t, bb, trig, stateH);
}

// ---- passA: pivots 15..24. Block = 32 contiguous spectators (slo) x 1024
// combos. Merged dword gathers/stores (lane-pairing); scalar fp16 LDS
// exchange (64 KiB -> 2 blocks/CU); packed rotations (se = +s uniform).
// Unchanged from round 10.
template<int L, bool FIN>
__global__ __launch_bounds__(1024, 4) void kpassA(uint16_t* __restrict__ stateH,
                                                  const float* __restrict__ trig,
                                                  float* __restrict__ outp)
{
  __shared__ __align__(16) uint16_t ldsH[32768];   // 64 KiB
  __shared__ float wsum[16];
  const uint32_t t = threadIdx.x;
  const uint32_t sbase = (uint32_t)blockIdx.x << 5;   // bits 5..14
  const float2* cs = (const float2*)(trig + 50 * L) + 15;
  const uint32_t slo = t & 31u;
  const uint32_t yf  = t >> 5;
  const uint32_t odd = t & 1u;
  // R0: register dims = pivots 15..19; yf -> pivots 20..24.
  uint32_t cy = 0u;
#pragma unroll
  for (int k = 0; k < 5; ++k) cy ^= ((yf >> k) & 1u) ? MK.M[L][20 + k] : 0u;
  const uint32_t A0 = sbase ^ slo ^ cy;
  v2f q[16];
  // merged gathers: pair (x, x^1) via M[L][15]; shfl_xor(1) redistributes.
#pragma unroll
  for (uint32_t g = 0; g < 16; ++g) {
    const uint32_t ax = (A0 ^ kxorB(L, 15, 2*g) ^ (odd ? MK.M[L][15] : 0u)) & ~1u;
    const uint32_t d  = *(const uint32_t*)(stateH + ax);
    const uint32_t dp = __shfl_xor(d, 1, 64);
    q[g].x = h2fu(odd ? (dp >> 16) : d);
    q[g].y = h2fu(odd ? (d >> 16)  : dp);
  }
  {
    float se5[5];
#pragma unroll
    for (int j = 0; j < 5; ++j) se5[j] = cs[j].y;
    rot_pow2<0>(q, cs, se5);
  }
  // exchange write: scalar fp16, slot (yf<<10)|(x<<5)|slo.
  {
    const uint32_t wb = (yf << 10) + slo;
#pragma unroll
    for (uint32_t g = 0; g < 16; ++g) {
      ldsH[wb + ((2*g) << 5)]   = f2hs(q[g].x);
      ldsH[wb + ((2*g+1) << 5)] = f2hs(q[g].y);
    }
  }
  __syncthreads();
  // R1: register dims = pivots 20..24; yf -> pivots 15..19.
  uint32_t cumt = 0u;
#pragma unroll
  for (int k = 0; k < 5; ++k) cumt ^= ((yf >> k) & 1u) ? MK.M[L][15 + k] : 0u;
  const uint32_t Ab = sbase ^ slo ^ cumt;
  {
    const uint32_t rb = (yf << 5) + slo;
#pragma unroll
    for (uint32_t g = 0; g < 16; ++g) {
      q[g].x = h2fs(ldsH[rb + ((2*g) << 10)]);
      q[g].y = h2fs(ldsH[rb + ((2*g+1) << 10)]);
    }
  }
  {
    float se5[5];
#pragma unroll
    for (int j = 0; j < 5; ++j) se5[j] = cs[5 + j].y;
    rot_pow2<5>(q, cs, se5);
  }
  if (!FIN) {
    // merged stores: pair (x, x^1) via M[L][20]; even lanes store x-dword,
    // odd lanes x^1-dword; one unpredicated 64-lane store per pair.
#pragma unroll
    for (uint32_t g = 0; g < 16; ++g) {
      const float p0 = __shfl_xor(q[g].x, 1, 64);
      const float p1 = __shfl_xor(q[g].y, 1, 64);
      const uint32_t ad = (Ab ^ kxorB(L, 20, 2*g) ^ (odd ? MK.M[L][20] : 0u)) & ~1u;
      const uint32_t val = odd ? pkh(p1, q[g].y) : pkh(q[g].x, p0);
      *(uint32_t*)(stateH + ad) = val;
    }
  } else {
    constexpr uint32_t pz =
        (cpar(MK.M[L][20] & MK.fz) << 0) | (cpar(MK.M[L][21] & MK.fz) << 1) |
        (cpar(MK.M[L][22] & MK.fz) << 2) | (cpar(MK.M[L][23] & MK.fz) << 3) |
        (cpar(MK.M[L][24] & MK.fz) << 4);
    float acc = 0.0f;
#pragma unroll
    for (uint32_t g = 0; g < 16; ++g) {
      const v2f sq = q[g] * q[g];
      acc += cpar((2*g) & pz)   ? -sq.x : sq.x;
      acc += cpar((2*g+1) & pz) ? -sq.y : sq.y;
    }
    if (__builtin_popcount(Ab & MK.fz) & 1) acc = -acc;
#pragma unroll
    for (int off = 32; off >= 1; off >>= 1) acc += __shfl_down(acc, off, 64);
    if ((t & 63u) == 0u) wsum[t >> 6] = acc;
    __syncthreads();
    if (t == 0) {
      float ssum = 0.0f;
#pragma unroll
      for (int w2 = 0; w2 < 16; ++w2) ssum += wsum[w2];
      atomicAdd(outp, ssum);
    }
  }
}

extern "C" void kernel_launch(void* const* d_in, const int* in_sizes, int n_in,
                              void* d_out, int out_size, void* d_ws, size_t ws_size,
                              hipStream_t stream)
{
  (void)in_sizes; (void)n_in; (void)out_size; (void)ws_size;
  const float* theta = (const float*)d_in[0];
  float* outp  = (float*)d_out;
  uint16_t* stateH = (uint16_t*)d_ws;                              // 2^25 halves
  float* trig  = (float*)((char*)d_ws + (size_t)(1u << 25) * 2u);  // 400 floats

  kprep<<<1, 256, 0, stream>>>(theta, trig, outp);
  kinit<<<1024, 1024, 0, stream>>>(stateH, trig);
  kpassA<1, false><<<1024, 1024, 0, stream>>>(stateH, trig, outp);
  kpassB<2><<<1024, 1024, 0, stream>>>(stateH, trig);
  kpassA<2, false><<<1024, 1024, 0, stream>>>(stateH, trig, outp);
  kpassB<3><<<1024, 1024, 0, stream>>>(stateH, trig);
  kpassA<3, false><<<1024, 1024, 0, stream>>>(stateH, trig, outp);
  kpassB<4><<<1024, 1024, 0, stream>>>(stateH, trig);
  kpassA<4, false><<<1024, 1024, 0, stream>>>(stateH, trig, outp);
  kpassB<5><<<1024, 1024, 0, stream>>>(stateH, trig);
  kpassA<5, false><<<1024, 1024, 0, stream>>>(stateH, trig, outp);
  kpassB<6><<<1024, 1024, 0, stream>>>(stateH, trig);
  kpassA<6, false><<<1024, 1024, 0, stream>>>(stateH, trig, outp);
  kpassB<7><<<1024, 1024, 0, stream>>>(stateH, trig);
  kpassA<7, true><<<1024, 1024, 0, stream>>>(stateH, trig, outp);
}

// Round 12
// 590.096 us; speedup vs baseline: 1.7270x; 1.0083x over previous
//
#include <hip/hip_runtime.h>
#include <hip/hip_fp16.h>
#include <stdint.h>

// 25-qubit, 8-layer RY + CNOT-chain circuit, output <Z_q0>.
// CNOT chains deferred into a GF(2) change-of-basis; only 200 RYs touch the
// state (2^25 fp16 = 64 MiB in d_ws). Arithmetic in f32, packed (v_pk_*).
// Round 12: identical to round 11 EXCEPT __launch_bounds__(1024, 8) on the
// three big kernels. Theory: at (1024,4) with 64 KiB LDS the compiler
// AGPR-shuffles (VGPR_Count 40 / SGPR 32 signature, like round 8), pushing
// per-wave arch+acc past 64 and silently blocking the 2nd co-resident block
// (occupancy stuck at the 1-block value 35%). The packed kernel's true need
// is ~52 regs (round-10 measurement at relaxed cap), so a hard 64 cap fits
// with no spill/AGPR and enables 2 blocks/CU phase interleaving.

#define NQ 25
#define DEPTH 8

typedef float v2f __attribute__((ext_vector_type(2)));

struct MaskSet {
  uint32_t M[DEPTH][NQ];   // M[l][b] = column b of W_l (pairing masks)
  uint32_t F[DEPTH][NQ];   // F[l][b] = row b of W_l^-1 (orientation functionals)
  uint32_t fz;             // final Z functional (row 24 of W_8^-1)
};

__host__ __device__ constexpr MaskSet buildMasks() {
  MaskSet r{};
  uint32_t col[NQ] = {}, inv[NQ] = {};
  for (int j = 0; j < NQ; ++j) { col[j] = 1u << j; inv[j] = 1u << j; }
  for (int l = 0; l < DEPTH; ++l) {
    for (int b = 0; b < NQ; ++b) { r.M[l][b] = col[b]; r.F[l][b] = inv[b]; }
    for (int w = 0; w < NQ - 1; ++w) {   // CNOT chain of layer l
      const int cb = 24 - w, tb = 23 - w;
      col[cb] ^= col[tb];
      inv[tb] ^= inv[cb];
    }
  }
  r.fz = inv[24];
  return r;
}

constexpr MaskSet MK = buildMasks();

// Half-index swizzle for 2^15-half LDS: XOR bits 3..5 with bits 6..8.
// Linear over GF(2); preserves 8-half (16B) groups -> b128-friendly.
__host__ __device__ constexpr uint32_t hswz(uint32_t h) { return h ^ ((h >> 3) & 0x38u); }

__host__ __device__ constexpr uint32_t kxorB(int L, int d0, uint32_t y) {
  uint32_t a = 0;
  for (int i = 0; i < 5; ++i) if ((y >> i) & 1u) a ^= MK.M[L][d0 + i];
  return a;
}

__host__ __device__ constexpr uint32_t cpar(uint32_t x) {
  uint32_t p = 0;
  for (int i = 0; i < 32; ++i) p ^= (x >> i) & 1u;
  return p;
}

// Evenness functional for R2's low-bit: bit0 of B2(t) = parity(t & r2mask(L)).
__host__ __device__ constexpr uint32_t r2mask(int L) {
  uint32_t r = 0;
  for (int i = 0; i < 5; ++i) {
    r |= (MK.M[L][i] & 1u) << i;           // t bits 0..4 -> dims 0..4
    r |= (MK.M[L][5 + i] & 1u) << (5 + i); // t bits 5..9 -> dims 5..9
  }
  return r;
}

__device__ __forceinline__ v2f vswap(v2f x) { return __builtin_shufflevector(x, x, 1, 0); }
__device__ __forceinline__ v2f vfma(v2f a, v2f b, v2f c) { return __builtin_elementwise_fma(a, b, c); }

__device__ __forceinline__ uint32_t pkh(float a, float b) {
  __half2 h = __floats2half2_rn(a, b);   // round-to-nearest (unbiased)
  return __builtin_bit_cast(uint32_t, h);
}
__device__ __forceinline__ uint32_t pkhv(v2f q) { return pkh(q.x, q.y); }
__device__ __forceinline__ v2f uphv(uint32_t w) {
  __half2 h = __builtin_bit_cast(__half2, w);
  float2 f = __half22float2(h);
  return (v2f){ f.x, f.y };
}
__device__ __forceinline__ float h2fu(uint32_t x) {   // low 16 bits -> f32
  __half h = __builtin_bit_cast(__half, (uint16_t)(x & 0xffffu));
  return __half2float(h);
}
__device__ __forceinline__ float h2fs(uint16_t x) {
  __half h = __builtin_bit_cast(__half, x);
  return __half2float(h);
}
__device__ __forceinline__ uint16_t f2hs(float x) {
  __half h = __float2half_rn(x);
  return __builtin_bit_cast(uint16_t, h);
}

__global__ void kprep(const float* __restrict__ theta, float* __restrict__ trig,
                      float* __restrict__ outp)
{
  int t = threadIdx.x;
  if (t == 0) outp[0] = 0.0f;
  if (t < 200) {
    int l = t / 25, b = t % 25;            // b = bit position, qubit w = 24-b
    float th = theta[l * 25 + (24 - b)] * 0.5f;
    trig[2 * t]     = cosf(th);
    trig[2 * t + 1] = sinf(th);
  }
}

// Packed rotation for register-space dims (mask = 1<<j in register index,
// pack = register bit 0): uniform se, sigma(e) = bit j of e.
template<int JLO>
__device__ __forceinline__ void rot_pow2(v2f (&q)[16], const float2* cs,
                                         const float* se5)
{
#pragma unroll
  for (int j = 0; j < 5; ++j) {
    const float c = cs[JLO + j].x;
    const float se = se5[j];
    const v2f c2 = { c, c };
    if (j == 0) {
      const v2f sv = { -se, se };
#pragma unroll
      for (uint32_t g = 0; g < 16; ++g)
        q[g] = vfma(sv, vswap(q[g]), c2 * q[g]);
    } else {
      const v2f sP = { se, se }, sM = { -se, -se };
      const uint32_t mh = 1u << (j - 1);
#pragma unroll
      for (uint32_t g = 0; g < 16; ++g) {
        const uint32_t h = g ^ mh;
        if (h < g) continue;
        const v2f a = q[g], b = q[h];
        q[g] = vfma(sM, b, c2 * a);
        q[h] = vfma(sP, a, c2 * b);
      }
    }
  }
}

// ---- passB tail: R0 (general 5-bit masks) -> fp16 LDS (b128 write) -> R1
//      (scalar u16 reads) -> writeback (no pre-barrier; bijective slots) ->
//      R2 -> merged full-wave fp16 dword stores. 2 barriers total.
template<int L>
__device__ __forceinline__ void passB_tail(v2f (&q)[16], uint16_t* ldsH,
                                           const uint32_t t, const uint32_t bb,
                                           const float* __restrict__ trig,
                                           uint16_t* __restrict__ stateH)
{
  const float2* cs = (const float2*)(trig + 50 * L);
  // R0: dims 0..4, masks M[L][j]&31 (general), sigma(e) = parity(e & fj5).
#pragma unroll
  for (int j = 0; j < 5; ++j) {
    const float2 w = cs[j];
    const float c = w.x, s = w.y;
    const float se = (__builtin_popcount((bb | (t << 5)) & MK.F[L][j]) & 1) ? -s : s;
    const uint32_t mmj = MK.M[L][j] & 31u;
    const uint32_t fj5 = MK.F[L][j] & 31u;
    const uint32_t mh = mmj >> 1;
    const bool sw = (mmj & 1u) != 0u;
    const v2f c2 = { c, c };
    const v2f sOdd = (fj5 & 1u) ? (v2f){ se, -se } : (v2f){ se, se };
    const v2f sEvn = (fj5 & 1u) ? (v2f){ -se, se } : (v2f){ -se, -se };
#pragma unroll
    for (uint32_t g = 0; g < 16; ++g) {
      const uint32_t h = g ^ mh;
      if (h < g) continue;
      const v2f a = q[g], b = q[h];
      const v2f pa = sw ? vswap(b) : b;
      const v2f sa = (__builtin_popcount(g & (fj5 >> 1)) & 1) ? sOdd : sEvn;
      q[g] = vfma(sa, pa, c2 * a);
      if (h != g) {
        const v2f pb = sw ? vswap(a) : a;
        const v2f sb2 = (__builtin_popcount(h & (fj5 >> 1)) & 1) ? sOdd : sEvn;
        q[h] = vfma(sb2, pb, c2 * b);
      }
    }
  }
  // exchange 1: own segment, 8 halves per b128 (hswz layout), 4 insts
  {
    uint4* l4 = (uint4*)ldsH;
#pragma unroll
    for (uint32_t k = 0; k < 4; ++k) {
      uint4 d = { pkhv(q[4*k+0]), pkhv(q[4*k+1]), pkhv(q[4*k+2]), pkhv(q[4*k+3]) };
      l4[hswz((t << 5) + 8u * k) >> 3] = d;
    }
  }
  __syncthreads();
  // R1: dims 5..9; thread coords: dims 0..4 <- t bits 0..4, dims 10..14 <- t bits 5..9
  uint32_t B1 = 0u;
#pragma unroll
  for (int i = 0; i < 5; ++i) B1 ^= ((t >> i) & 1u) ? MK.M[L][i] : 0u;
#pragma unroll
  for (int i = 0; i < 5; ++i) B1 ^= ((t >> (5 + i)) & 1u) ? MK.M[L][10 + i] : 0u;
  const uint32_t B1s = hswz(B1);
#pragma unroll
  for (uint32_t g = 0; g < 16; ++g) {
    q[g].x = h2fs(ldsH[B1s ^ hswz(kxorB(L, 5, 2*g))]);
    q[g].y = h2fs(ldsH[B1s ^ hswz(kxorB(L, 5, 2*g+1))]);
  }
  {
    float se5[5];
#pragma unroll
    for (int j = 0; j < 5; ++j) {
      const float s = cs[5 + j].y;
      se5[j] = (__builtin_popcount(bb & MK.F[L][5 + j]) & 1) ? -s : s;
    }
    rot_pow2<5>(q, cs, se5);
  }
  // writeback to own read slots — no barrier needed before (slot->thread map
  // is bijective; each thread writes exactly what it read)
#pragma unroll
  for (uint32_t g = 0; g < 16; ++g) {
    ldsH[B1s ^ hswz(kxorB(L, 5, 2*g))]   = f2hs(q[g].x);
    ldsH[B1s ^ hswz(kxorB(L, 5, 2*g+1))] = f2hs(q[g].y);
  }
  __syncthreads();
  // R2: dims 10..14; thread coords: dims 0..4 <- t bits 0..4, dims 5..9 <- t bits 5..9
  uint32_t B2 = 0u;
#pragma unroll
  for (int i = 0; i < 5; ++i) B2 ^= ((t >> i) & 1u) ? MK.M[L][i] : 0u;
#pragma unroll
  for (int i = 0; i < 5; ++i) B2 ^= ((t >> (5 + i)) & 1u) ? MK.M[L][5 + i] : 0u;
  const uint32_t B2s = hswz(B2);
#pragma unroll
  for (uint32_t g = 0; g < 16; ++g) {
    q[g].x = h2fs(ldsH[B2s ^ hswz(kxorB(L, 10, 2*g))]);
    q[g].y = h2fs(ldsH[B2s ^ hswz(kxorB(L, 10, 2*g+1))]);
  }
  {
    float se5[5];
#pragma unroll
    for (int j = 0; j < 5; ++j) {
      const float s = cs[10 + j].y;
      se5[j] = (__builtin_popcount(bb & MK.F[L][10 + j]) & 1) ? -s : s;
    }
    rot_pow2<10>(q, cs, se5);
  }
  // merged store: pair (y, y^1) via M[L][10]; cls = bit0 of own address;
  // partner lane = t^1 (M[L][0]=e0). One unpredicated 64-lane dword store
  // per pair = full 128B-line coverage.
  {
    constexpr uint32_t rm = r2mask(L);
    const uint32_t cls = (uint32_t)__builtin_popcount(t & rm) & 1u;
    const uint32_t sb = bb ^ B2;
#pragma unroll
    for (uint32_t g = 0; g < 16; ++g) {
      const float p0 = __shfl_xor(q[g].x, 1, 64);
      const float p1 = __shfl_xor(q[g].y, 1, 64);
      const uint32_t ad = (sb ^ kxorB(L, 10, 2*g) ^ (cls ? MK.M[L][10] : 0u)) & ~1u;
      const uint32_t val = cls ? pkh(p1, q[g].y) : pkh(q[g].x, p0);
      *(uint32_t*)(stateH + ad) = val;
    }
  }
}

template<int L>
__global__ __launch_bounds__(1024, 8) void kpassB(uint16_t* __restrict__ stateH,
                                                  const float* __restrict__ trig)
{
  __shared__ __align__(16) uint16_t ldsH[32768];   // 64 KiB -> 2 blocks/CU
  const uint32_t t = threadIdx.x;
  const uint32_t bb = (uint32_t)blockIdx.x << 15;
  // direct load: thread t owns 64 contiguous bytes (32 halves, tile order)
  v2f q[16];
  {
    const uint4* g4 = (const uint4*)(stateH + bb + (t << 5));
#pragma unroll
    for (uint32_t k = 0; k < 4; ++k) {
      const uint4 d = g4[k];
      q[4*k+0] = uphv(d.x); q[4*k+1] = uphv(d.y);
      q[4*k+2] = uphv(d.z); q[4*k+3] = uphv(d.w);
    }
  }
  passB_tail<L>(q, ldsH, t, bb, trig, stateH);
}

// kinit: layer-0 product state built analytically in tile-address order
// (packed doubling tree), then layer-1 passB tail. Write-only pass.
__global__ __launch_bounds__(1024, 8) void kinit(uint16_t* __restrict__ stateH,
                                                 const float* __restrict__ trig)
{
  __shared__ __align__(16) uint16_t ldsH[32768];
  const uint32_t t = threadIdx.x;
  const uint32_t bb = (uint32_t)blockIdx.x << 15;
  const float2* cs0 = (const float2*)trig;       // layer 0, indexed by bit
  const uint32_t hi = bb | (t << 5);
  float pt = 1.0f;
#pragma unroll
  for (int b = 5; b < 25; ++b) {
    const float2 w = cs0[b];
    pt *= ((hi >> b) & 1u) ? w.y : w.x;
  }
  v2f q[16];
  {
    const float2 w0 = cs0[0];
    q[0] = (v2f){ pt * w0.x, pt * w0.y };
#pragma unroll
    for (int j = 1; j < 5; ++j) {
      const float2 w = cs0[j];
      const v2f wx = { w.x, w.x }, wy = { w.y, w.y };
#pragma unroll
      for (int g = 0; g < (1 << (j - 1)); ++g) {
        q[g | (1 << (j - 1))] = q[g] * wy;
        q[g] = q[g] * wx;
      }
    }
  }
  passB_tail<1>(q, ldsH, t, bb, trig, stateH);
}

// ---- passA: pivots 15..24. Block = 32 contiguous spectators (slo) x 1024
// combos. Merged dword gathers/stores (lane-pairing); scalar fp16 LDS
// exchange (64 KiB); packed rotations (se = +s uniform).
template<int L, bool FIN>
__global__ __launch_bounds__(1024, 8) void kpassA(uint16_t* __restrict__ stateH,
                                                  const float* __restrict__ trig,
                                                  float* __restrict__ outp)
{
  __shared__ __align__(16) uint16_t ldsH[32768];   // 64 KiB
  __shared__ float wsum[16];
  const uint32_t t = threadIdx.x;
  const uint32_t sbase = (uint32_t)blockIdx.x << 5;   // bits 5..14
  const float2* cs = (const float2*)(trig + 50 * L) + 15;
  const uint32_t slo = t & 31u;
  const uint32_t yf  = t >> 5;
  const uint32_t odd = t & 1u;
  // R0: register dims = pivots 15..19; yf -> pivots 20..24.
  uint32_t cy = 0u;
#pragma unroll
  for (int k = 0; k < 5; ++k) cy ^= ((yf >> k) & 1u) ? MK.M[L][20 + k] : 0u;
  const uint32_t A0 = sbase ^ slo ^ cy;
  v2f q[16];
  // merged gathers: pair (x, x^1) via M[L][15]; shfl_xor(1) redistributes.
#pragma unroll
  for (uint32_t g = 0; g < 16; ++g) {
    const uint32_t ax = (A0 ^ kxorB(L, 15, 2*g) ^ (odd ? MK.M[L][15] : 0u)) & ~1u;
    const uint32_t d  = *(const uint32_t*)(stateH + ax);
    const uint32_t dp = __shfl_xor(d, 1, 64);
    q[g].x = h2fu(odd ? (dp >> 16) : d);
    q[g].y = h2fu(odd ? (d >> 16)  : dp);
  }
  {
    float se5[5];
#pragma unroll
    for (int j = 0; j < 5; ++j) se5[j] = cs[j].y;
    rot_pow2<0>(q, cs, se5);
  }
  // exchange write: scalar fp16, slot (yf<<10)|(x<<5)|slo.
  {
    const uint32_t wb = (yf << 10) + slo;
#pragma unroll
    for (uint32_t g = 0; g < 16; ++g) {
      ldsH[wb + ((2*g) << 5)]   = f2hs(q[g].x);
      ldsH[wb + ((2*g+1) << 5)] = f2hs(q[g].y);
    }
  }
  __syncthreads();
  // R1: register dims = pivots 20..24; yf -> pivots 15..19.
  uint32_t cumt = 0u;
#pragma unroll
  for (int k = 0; k < 5; ++k) cumt ^= ((yf >> k) & 1u) ? MK.M[L][15 + k] : 0u;
  const uint32_t Ab = sbase ^ slo ^ cumt;
  {
    const uint32_t rb = (yf << 5) + slo;
#pragma unroll
    for (uint32_t g = 0; g < 16; ++g) {
      q[g].x = h2fs(ldsH[rb + ((2*g) << 10)]);
      q[g].y = h2fs(ldsH[rb + ((2*g+1) << 10)]);
    }
  }
  {
    float se5[5];
#pragma unroll
    for (int j = 0; j < 5; ++j) se5[j] = cs[5 + j].y;
    rot_pow2<5>(q, cs, se5);
  }
  if (!FIN) {
    // merged stores: pair (x, x^1) via M[L][20]; even lanes store x-dword,
    // odd lanes x^1-dword; one unpredicated 64-lane store per pair.
#pragma unroll
    for (uint32_t g = 0; g < 16; ++g) {
      const float p0 = __shfl_xor(q[g].x, 1, 64);
      const float p1 = __shfl_xor(q[g].y, 1, 64);
      const uint32_t ad = (Ab ^ kxorB(L, 20, 2*g) ^ (odd ? MK.M[L][20] : 0u)) & ~1u;
      const uint32_t val = odd ? pkh(p1, q[g].y) : pkh(q[g].x, p0);
      *(uint32_t*)(stateH + ad) = val;
    }
  } else {
    constexpr uint32_t pz =
        (cpar(MK.M[L][20] & MK.fz) << 0) | (cpar(MK.M[L][21] & MK.fz) << 1) |
        (cpar(MK.M[L][22] & MK.fz) << 2) | (cpar(MK.M[L][23] & MK.fz) << 3) |
        (cpar(MK.M[L][24] & MK.fz) << 4);
    float acc = 0.0f;
#pragma unroll
    for (uint32_t g = 0; g < 16; ++g) {
      const v2f sq = q[g] * q[g];
      acc += cpar((2*g) & pz)   ? -sq.x : sq.x;
      acc += cpar((2*g+1) & pz) ? -sq.y : sq.y;
    }
    if (__builtin_popcount(Ab & MK.fz) & 1) acc = -acc;
#pragma unroll
    for (int off = 32; off >= 1; off >>= 1) acc += __shfl_down(acc, off, 64);
    if ((t & 63u) == 0u) wsum[t >> 6] = acc;
    __syncthreads();
    if (t == 0) {
      float ssum = 0.0f;
#pragma unroll
      for (int w2 = 0; w2 < 16; ++w2) ssum += wsum[w2];
      atomicAdd(outp, ssum);
    }
  }
}

extern "C" void kernel_launch(void* const* d_in, const int* in_sizes, int n_in,
                              void* d_out, int out_size, void* d_ws, size_t ws_size,
                              hipStream_t stream)
{
  (void)in_sizes; (void)n_in; (void)out_size; (void)ws_size;
  const float* theta = (const float*)d_in[0];
  float* outp  = (float*)d_out;
  uint16_t* stateH = (uint16_t*)d_ws;                              // 2^25 halves
  float* trig  = (float*)((char*)d_ws + (size_t)(1u << 25) * 2u);  // 400 floats

  kprep<<<1, 256, 0, stream>>>(theta, trig, outp);
  kinit<<<1024, 1024, 0, stream>>>(stateH, trig);
  kpassA<1, false><<<1024, 1024, 0, stream>>>(stateH, trig, outp);
  kpassB<2><<<1024, 1024, 0, stream>>>(stateH, trig);
  kpassA<2, false><<<1024, 1024, 0, stream>>>(stateH, trig, outp);
  kpassB<3><<<1024, 1024, 0, stream>>>(stateH, trig);
  kpassA<3, false><<<1024, 1024, 0, stream>>>(stateH, trig, outp);
  kpassB<4><<<1024, 1024, 0, stream>>>(stateH, trig);
  kpassA<4, false><<<1024, 1024, 0, stream>>>(stateH, trig, outp);
  kpassB<5><<<1024, 1024, 0, stream>>>(stateH, trig);
  kpassA<5, false><<<1024, 1024, 0, stream>>>(stateH, trig, outp);
  kpassB<6><<<1024, 1024, 0, stream>>>(stateH, trig);
  kpassA<6, false><<<1024, 1024, 0, stream>>>(stateH, trig, outp);
  kpassB<7><<<1024, 1024, 0, stream>>>(stateH, trig);
  kpassA<7, true><<<1024, 1024, 0, stream>>>(stateH, trig, outp);
}

// Round 13
// 573.480 us; speedup vs baseline: 1.7770x; 1.0290x over previous
//
#include <hip/hip_runtime.h>
#include <hip/hip_fp16.h>
#include <stdint.h>

// 25-qubit, 8-layer RY + CNOT-chain circuit, output <Z_q0>.
// CNOT chains deferred into a GF(2) change-of-basis; only 200 RYs touch the
// state (2^25 fp16 = 64 MiB in d_ws).
// Round 13: working set = packed _Float16 vectors (v_pk_fma_f16). Same
// per-inst element rate as pk_f32, but: (1) all f16<->f32 conversions at
// load/exchange/store become bitcasts/bit-blends (~30% VALU cut), (2) q
// shrinks 32->16 VGPRs -> genuinely fits the (1024,8) 64-reg cap -> round-12
// spill (+38 MB/pass scratch) eliminated, (3) merged stores/gathers need 1
// dword shfl per pair instead of 2. FIN unpacks to f32 before squaring.

#define NQ 25
#define DEPTH 8

typedef _Float16 f16;
typedef f16 h2 __attribute__((ext_vector_type(2)));

struct MaskSet {
  uint32_t M[DEPTH][NQ];   // M[l][b] = column b of W_l (pairing masks)
  uint32_t F[DEPTH][NQ];   // F[l][b] = row b of W_l^-1 (orientation functionals)
  uint32_t fz;             // final Z functional (row 24 of W_8^-1)
};

__host__ __device__ constexpr MaskSet buildMasks() {
  MaskSet r{};
  uint32_t col[NQ] = {}, inv[NQ] = {};
  for (int j = 0; j < NQ; ++j) { col[j] = 1u << j; inv[j] = 1u << j; }
  for (int l = 0; l < DEPTH; ++l) {
    for (int b = 0; b < NQ; ++b) { r.M[l][b] = col[b]; r.F[l][b] = inv[b]; }
    for (int w = 0; w < NQ - 1; ++w) {   // CNOT chain of layer l
      const int cb = 24 - w, tb = 23 - w;
      col[cb] ^= col[tb];
      inv[tb] ^= inv[cb];
    }
  }
  r.fz = inv[24];
  return r;
}

constexpr MaskSet MK = buildMasks();

// Half-index swizzle for 2^15-half LDS: XOR bits 3..5 with bits 6..8.
// Linear over GF(2); preserves 8-half (16B) groups -> b128-friendly.
__host__ __device__ constexpr uint32_t hswz(uint32_t h) { return h ^ ((h >> 3) & 0x38u); }

__host__ __device__ constexpr uint32_t kxorB(int L, int d0, uint32_t y) {
  uint32_t a = 0;
  for (int i = 0; i < 5; ++i) if ((y >> i) & 1u) a ^= MK.M[L][d0 + i];
  return a;
}

__host__ __device__ constexpr uint32_t cpar(uint32_t x) {
  uint32_t p = 0;
  for (int i = 0; i < 32; ++i) p ^= (x >> i) & 1u;
  return p;
}

// Evenness functional for R2's low-bit: bit0 of B2(t) = parity(t & r2mask(L)).
__host__ __device__ constexpr uint32_t r2mask(int L) {
  uint32_t r = 0;
  for (int i = 0; i < 5; ++i) {
    r |= (MK.M[L][i] & 1u) << i;           // t bits 0..4 -> dims 0..4
    r |= (MK.M[L][5 + i] & 1u) << (5 + i); // t bits 5..9 -> dims 5..9
  }
  return r;
}

__device__ __forceinline__ h2 h2bc(uint32_t u) { return __builtin_bit_cast(h2, u); }
__device__ __forceinline__ uint32_t u32bc(h2 x) { return __builtin_bit_cast(uint32_t, x); }
__device__ __forceinline__ h2 hswap(h2 x) { return __builtin_shufflevector(x, x, 1, 0); }
__device__ __forceinline__ h2 hset(float a, float b) { return (h2){ (f16)a, (f16)b }; }
// a*b+c with default HIP fp contraction -> v_pk_fma_f16
__device__ __forceinline__ h2 hfma(h2 a, h2 b, h2 c) { return a * b + c; }

__global__ void kprep(const float* __restrict__ theta, float* __restrict__ trig,
                      float* __restrict__ outp)
{
  int t = threadIdx.x;
  if (t == 0) outp[0] = 0.0f;
  if (t < 200) {
    int l = t / 25, b = t % 25;            // b = bit position, qubit w = 24-b
    float th = theta[l * 25 + (24 - b)] * 0.5f;
    trig[2 * t]     = cosf(th);
    trig[2 * t + 1] = sinf(th);
  }
}

// Packed rotation for register-space dims (mask = 1<<j in register index,
// pack = register bit 0): uniform se, sigma(e) = bit j of e.
template<int JLO>
__device__ __forceinline__ void rot_pow2h(h2 (&q)[16], const float2* cs,
                                          const float* se5)
{
#pragma unroll
  for (int j = 0; j < 5; ++j) {
    const float c = cs[JLO + j].x;
    const float se = se5[j];
    const h2 c2 = hset(c, c);
    if (j == 0) {
      const h2 sv = hset(-se, se);
#pragma unroll
      for (uint32_t g = 0; g < 16; ++g)
        q[g] = hfma(sv, hswap(q[g]), c2 * q[g]);
    } else {
      const h2 sP = hset(se, se), sM = hset(-se, -se);
      const uint32_t mh = 1u << (j - 1);
#pragma unroll
      for (uint32_t g = 0; g < 16; ++g) {
        const uint32_t h = g ^ mh;
        if (h < g) continue;
        const h2 a = q[g], b = q[h];
        q[g] = hfma(sM, b, c2 * a);
        q[h] = hfma(sP, a, c2 * b);
      }
    }
  }
}

// ---- passB tail: R0 (general 5-bit masks) -> fp16 LDS (b128 write) -> R1
//      (u16 pair reads) -> writeback (no pre-barrier; bijective slots) ->
//      R2 -> merged full-wave dword stores (bit-blend). 2 barriers total.
template<int L>
__device__ __forceinline__ void passB_tail(h2 (&q)[16], uint16_t* ldsH,
                                           const uint32_t t, const uint32_t bb,
                                           const float* __restrict__ trig,
                                           uint16_t* __restrict__ stateH)
{
  const float2* cs = (const float2*)(trig + 50 * L);
  // R0: dims 0..4, masks M[L][j]&31 (general), sigma(e) = parity(e & fj5).
#pragma unroll
  for (int j = 0; j < 5; ++j) {
    const float2 w = cs[j];
    const float c = w.x, s = w.y;
    const float se = (__builtin_popcount((bb | (t << 5)) & MK.F[L][j]) & 1) ? -s : s;
    const uint32_t mmj = MK.M[L][j] & 31u;
    const uint32_t fj5 = MK.F[L][j] & 31u;
    const uint32_t mh = mmj >> 1;
    const bool sw = (mmj & 1u) != 0u;
    const h2 c2 = hset(c, c);
    const h2 sOdd = (fj5 & 1u) ? hset(se, -se) : hset(se, se);
    const h2 sEvn = (fj5 & 1u) ? hset(-se, se) : hset(-se, -se);
#pragma unroll
    for (uint32_t g = 0; g < 16; ++g) {
      const uint32_t h = g ^ mh;
      if (h < g) continue;
      const h2 a = q[g], b = q[h];
      const h2 pa = sw ? hswap(b) : b;
      const h2 sa = (__builtin_popcount(g & (fj5 >> 1)) & 1) ? sOdd : sEvn;
      q[g] = hfma(sa, pa, c2 * a);
      if (h != g) {
        const h2 pb = sw ? hswap(a) : a;
        const h2 sb2 = (__builtin_popcount(h & (fj5 >> 1)) & 1) ? sOdd : sEvn;
        q[h] = hfma(sb2, pb, c2 * b);
      }
    }
  }
  // exchange 1: own segment, 8 halves per b128 (hswz layout) — pure bitcast
  {
    uint4* l4 = (uint4*)ldsH;
#pragma unroll
    for (uint32_t k = 0; k < 4; ++k) {
      uint4 d = { u32bc(q[4*k+0]), u32bc(q[4*k+1]), u32bc(q[4*k+2]), u32bc(q[4*k+3]) };
      l4[hswz((t << 5) + 8u * k) >> 3] = d;
    }
  }
  __syncthreads();
  // R1: dims 5..9; thread coords: dims 0..4 <- t bits 0..4, dims 10..14 <- t bits 5..9
  uint32_t B1 = 0u;
#pragma unroll
  for (int i = 0; i < 5; ++i) B1 ^= ((t >> i) & 1u) ? MK.M[L][i] : 0u;
#pragma unroll
  for (int i = 0; i < 5; ++i) B1 ^= ((t >> (5 + i)) & 1u) ? MK.M[L][10 + i] : 0u;
  const uint32_t B1s = hswz(B1);
#pragma unroll
  for (uint32_t g = 0; g < 16; ++g) {
    const uint32_t lo = ldsH[B1s ^ hswz(kxorB(L, 5, 2*g))];
    const uint32_t hi = ldsH[B1s ^ hswz(kxorB(L, 5, 2*g+1))];
    q[g] = h2bc(lo | (hi << 16));
  }
  {
    float se5[5];
#pragma unroll
    for (int j = 0; j < 5; ++j) {
      const float s = cs[5 + j].y;
      se5[j] = (__builtin_popcount(bb & MK.F[L][5 + j]) & 1) ? -s : s;
    }
    rot_pow2h<5>(q, cs, se5);
  }
  // writeback to own read slots — no barrier needed before (bijective slots)
#pragma unroll
  for (uint32_t g = 0; g < 16; ++g) {
    const uint32_t u = u32bc(q[g]);
    ldsH[B1s ^ hswz(kxorB(L, 5, 2*g))]   = (uint16_t)u;
    ldsH[B1s ^ hswz(kxorB(L, 5, 2*g+1))] = (uint16_t)(u >> 16);
  }
  __syncthreads();
  // R2: dims 10..14; thread coords: dims 0..4 <- t bits 0..4, dims 5..9 <- t bits 5..9
  uint32_t B2 = 0u;
#pragma unroll
  for (int i = 0; i < 5; ++i) B2 ^= ((t >> i) & 1u) ? MK.M[L][i] : 0u;
#pragma unroll
  for (int i = 0; i < 5; ++i) B2 ^= ((t >> (5 + i)) & 1u) ? MK.M[L][5 + i] : 0u;
  const uint32_t B2s = hswz(B2);
#pragma unroll
  for (uint32_t g = 0; g < 16; ++g) {
    const uint32_t lo = ldsH[B2s ^ hswz(kxorB(L, 10, 2*g))];
    const uint32_t hi = ldsH[B2s ^ hswz(kxorB(L, 10, 2*g+1))];
    q[g] = h2bc(lo | (hi << 16));
  }
  {
    float se5[5];
#pragma unroll
    for (int j = 0; j < 5; ++j) {
      const float s = cs[10 + j].y;
      se5[j] = (__builtin_popcount(bb & MK.F[L][10 + j]) & 1) ? -s : s;
    }
    rot_pow2h<10>(q, cs, se5);
  }
  // merged store: pair (2g, 2g+1) via M[L][10]; cls = bit0 of own address;
  // partner lane = t^1 (M[L][0]=e0). One dword shfl + bit-blend per pair.
  {
    constexpr uint32_t rm = r2mask(L);
    const uint32_t cls = (uint32_t)__builtin_popcount(t & rm) & 1u;
    const uint32_t sb = bb ^ B2;
#pragma unroll
    for (uint32_t g = 0; g < 16; ++g) {
      const uint32_t d = u32bc(q[g]);
      const uint32_t p = (uint32_t)__shfl_xor((int)d, 1, 64);
      const uint32_t ad = (sb ^ kxorB(L, 10, 2*g) ^ (cls ? MK.M[L][10] : 0u)) & ~1u;
      const uint32_t val = cls ? ((p >> 16) | (d & 0xffff0000u))
                               : ((d & 0xffffu) | (p << 16));
      *(uint32_t*)(stateH + ad) = val;
    }
  }
}

template<int L>
__global__ __launch_bounds__(1024, 8) void kpassB(uint16_t* __restrict__ stateH,
                                                  const float* __restrict__ trig)
{
  __shared__ __align__(16) uint16_t ldsH[32768];   // 64 KiB -> 2 blocks/CU
  const uint32_t t = threadIdx.x;
  const uint32_t bb = (uint32_t)blockIdx.x << 15;
  // direct load: thread t owns 64 contiguous bytes (32 halves, tile order)
  h2 q[16];
  {
    const uint4* g4 = (const uint4*)(stateH + bb + (t << 5));
#pragma unroll
    for (uint32_t k = 0; k < 4; ++k) {
      const uint4 d = g4[k];
      q[4*k+0] = h2bc(d.x); q[4*k+1] = h2bc(d.y);
      q[4*k+2] = h2bc(d.z); q[4*k+3] = h2bc(d.w);
    }
  }
  passB_tail<L>(q, ldsH, t, bb, trig, stateH);
}

// kinit: layer-0 product state built analytically in tile-address order,
// then layer-1 passB tail. Write-only pass. Tree in f32, pack to h2 last.
__global__ __launch_bounds__(1024, 8) void kinit(uint16_t* __restrict__ stateH,
                                                 const float* __restrict__ trig)
{
  __shared__ __align__(16) uint16_t ldsH[32768];
  const uint32_t t = threadIdx.x;
  const uint32_t bb = (uint32_t)blockIdx.x << 15;
  const float2* cs0 = (const float2*)trig;       // layer 0, indexed by bit
  const uint32_t hi = bb | (t << 5);
  float pt = 1.0f;
#pragma unroll
  for (int b = 5; b < 25; ++b) {
    const float2 w = cs0[b];
    pt *= ((hi >> b) & 1u) ? w.y : w.x;
  }
  // f32 tree over element bits 1..4 (g bits 0..3), then bit 0 into halves
  float v16[16];
  v16[0] = pt;
#pragma unroll
  for (int j = 1; j < 5; ++j) {
    const float2 w = cs0[j];
#pragma unroll
    for (int g = 0; g < (1 << (j - 1)); ++g) {
      v16[g | (1 << (j - 1))] = v16[g] * w.y;
      v16[g] = v16[g] * w.x;
    }
  }
  h2 q[16];
  {
    const float2 w0 = cs0[0];
#pragma unroll
    for (int g = 0; g < 16; ++g) q[g] = hset(v16[g] * w0.x, v16[g] * w0.y);
  }
  passB_tail<1>(q, ldsH, t, bb, trig, stateH);
}

// ---- passA: pivots 15..24. Block = 32 contiguous spectators (slo) x 1024
// combos. Merged dword gathers/stores (lane-pairing, bit-blend); scalar u16
// LDS exchange (64 KiB); packed fp16 rotations (se = +s uniform).
template<int L, bool FIN>
__global__ __launch_bounds__(1024, 8) void kpassA(uint16_t* __restrict__ stateH,
                                                  const float* __restrict__ trig,
                                                  float* __restrict__ outp)
{
  __shared__ __align__(16) uint16_t ldsH[32768];   // 64 KiB
  __shared__ float wsum[16];
  const uint32_t t = threadIdx.x;
  const uint32_t sbase = (uint32_t)blockIdx.x << 5;   // bits 5..14
  const float2* cs = (const float2*)(trig + 50 * L) + 15;
  const uint32_t slo = t & 31u;
  const uint32_t yf  = t >> 5;
  const uint32_t odd = t & 1u;
  // R0: register dims = pivots 15..19; yf -> pivots 20..24.
  uint32_t cy = 0u;
#pragma unroll
  for (int k = 0; k < 5; ++k) cy ^= ((yf >> k) & 1u) ? MK.M[L][20 + k] : 0u;
  const uint32_t A0 = sbase ^ slo ^ cy;
  h2 q[16];
  // merged gathers: pair (2g, 2g+1) via M[L][15]; 1 dword shfl + blend.
#pragma unroll
  for (uint32_t g = 0; g < 16; ++g) {
    const uint32_t ax = (A0 ^ kxorB(L, 15, 2*g) ^ (odd ? MK.M[L][15] : 0u)) & ~1u;
    const uint32_t d  = *(const uint32_t*)(stateH + ax);
    const uint32_t p  = (uint32_t)__shfl_xor((int)d, 1, 64);
    q[g] = h2bc(odd ? ((p >> 16) | (d & 0xffff0000u))
                    : ((d & 0xffffu) | (p << 16)));
  }
  {
    float se5[5];
#pragma unroll
    for (int j = 0; j < 5; ++j) se5[j] = cs[j].y;
    rot_pow2h<0>(q, cs, se5);
  }
  // exchange write: scalar u16, slot (yf<<10)|(x<<5)|slo.
  {
    const uint32_t wb = (yf << 10) + slo;
#pragma unroll
    for (uint32_t g = 0; g < 16; ++g) {
      const uint32_t u = u32bc(q[g]);
      ldsH[wb + ((2*g) << 5)]   = (uint16_t)u;
      ldsH[wb + ((2*g+1) << 5)] = (uint16_t)(u >> 16);
    }
  }
  __syncthreads();
  // R1: register dims = pivots 20..24; yf -> pivots 15..19.
  uint32_t cumt = 0u;
#pragma unroll
  for (int k = 0; k < 5; ++k) cumt ^= ((yf >> k) & 1u) ? MK.M[L][15 + k] : 0u;
  const uint32_t Ab = sbase ^ slo ^ cumt;
  {
    const uint32_t rb = (yf << 5) + slo;
#pragma unroll
    for (uint32_t g = 0; g < 16; ++g) {
      const uint32_t lo = ldsH[rb + ((2*g) << 10)];
      const uint32_t hi = ldsH[rb + ((2*g+1) << 10)];
      q[g] = h2bc(lo | (hi << 16));
    }
  }
  {
    float se5[5];
#pragma unroll
    for (int j = 0; j < 5; ++j) se5[j] = cs[5 + j].y;
    rot_pow2h<5>(q, cs, se5);
  }
  if (!FIN) {
    // merged stores: pair (2g, 2g+1) via M[L][20]; 1 dword shfl + blend.
#pragma unroll
    for (uint32_t g = 0; g < 16; ++g) {
      const uint32_t d = u32bc(q[g]);
      const uint32_t p = (uint32_t)__shfl_xor((int)d, 1, 64);
      const uint32_t ad = (Ab ^ kxorB(L, 20, 2*g) ^ (odd ? MK.M[L][20] : 0u)) & ~1u;
      const uint32_t val = odd ? ((p >> 16) | (d & 0xffff0000u))
                               : ((d & 0xffffu) | (p << 16));
      *(uint32_t*)(stateH + ad) = val;
    }
  } else {
    constexpr uint32_t pz =
        (cpar(MK.M[L][20] & MK.fz) << 0) | (cpar(MK.M[L][21] & MK.fz) << 1) |
        (cpar(MK.M[L][22] & MK.fz) << 2) | (cpar(MK.M[L][23] & MK.fz) << 3) |
        (cpar(MK.M[L][24] & MK.fz) << 4);
    float acc = 0.0f;
#pragma unroll
    for (uint32_t g = 0; g < 16; ++g) {
      const float x = (float)q[g].x;
      const float y = (float)q[g].y;
      acc += cpar((2*g) & pz)   ? -(x * x) : (x * x);
      acc += cpar((2*g+1) & pz) ? -(y * y) : (y * y);
    }
    if (__builtin_popcount(Ab & MK.fz) & 1) acc = -acc;
#pragma unroll
    for (int off = 32; off >= 1; off >>= 1) acc += __shfl_down(acc, off, 64);
    if ((t & 63u) == 0u) wsum[t >> 6] = acc;
    __syncthreads();
    if (t == 0) {
      float ssum = 0.0f;
#pragma unroll
      for (int w2 = 0; w2 < 16; ++w2) ssum += wsum[w2];
      atomicAdd(outp, ssum);
    }
  }
}

extern "C" void kernel_launch(void* const* d_in, const int* in_sizes, int n_in,
                              void* d_out, int out_size, void* d_ws, size_t ws_size,
                              hipStream_t stream)
{
  (void)in_sizes; (void)n_in; (void)out_size; (void)ws_size;
  const float* theta = (const float*)d_in[0];
  float* outp  = (float*)d_out;
  uint16_t* stateH = (uint16_t*)d_ws;                              // 2^25 halves
  float* trig  = (float*)((char*)d_ws + (size_t)(1u << 25) * 2u);  // 400 floats

  kprep<<<1, 256, 0, stream>>>(theta, trig, outp);
  kinit<<<1024, 1024, 0, stream>>>(stateH, trig);
  kpassA<1, false><<<1024, 1024, 0, stream>>>(stateH, trig, outp);
  kpassB<2><<<1024, 1024, 0, stream>>>(stateH, trig);
  kpassA<2, false><<<1024, 1024, 0, stream>>>(stateH, trig, outp);
  kpassB<3><<<1024, 1024, 0, stream>>>(stateH, trig);
  kpassA<3, false><<<1024, 1024, 0, stream>>>(stateH, trig, outp);
  kpassB<4><<<1024, 1024, 0, stream>>>(stateH, trig);
  kpassA<4, false><<<1024, 1024, 0, stream>>>(stateH, trig, outp);
  kpassB<5><<<1024, 1024, 0, stream>>>(stateH, trig);
  kpassA<5, false><<<1024, 1024, 0, stream>>>(stateH, trig, outp);
  kpassB<6><<<1024, 1024, 0, stream>>>(stateH, trig);
  kpassA<6, false><<<1024, 1024, 0, stream>>>(stateH, trig, outp);
  kpassB<7><<<1024, 1024, 0, stream>>>(stateH, trig);
  kpassA<7, true><<<1024, 1024, 0, stream>>>(stateH, trig, outp);
}

// Round 14
// 534.129 us; speedup vs baseline: 1.9079x; 1.0737x over previous
//
#include <hip/hip_runtime.h>
#include <hip/hip_fp16.h>
#include <stdint.h>

// 25-qubit, 8-layer RY + CNOT-chain circuit, output <Z_q0>.
// CNOT chains deferred into a GF(2) change-of-basis; only 200 RYs touch the
// state (2^25 fp16 = 64 MiB in d_ws). Packed fp16 arithmetic (v_pk_fma_f16).
// Round 14: kpassA gather phase restructured. Old: 16 scattered dword
// gathers (2x64B segments per wave-inst) + 16 shfl redistributions ->
// latency-bound (VALU 33% / HBM 36%). New: stage the block's full 64-KiB
// footprint into LDS with 4 dwordx4 loads/thread (16B/lane sweet spot;
// LDS half-idx = 8t + (k<<13) -> pure conflict-free b128 writes), then read
// R0 fragments from LDS (2-way banks = free), rotate, write back to the
// SAME bijective slots (no extra barrier), barrier, R1 as before. 2
// barriers total. kpassB/kinit unchanged from round 13 (573.5 us best).

#define NQ 25
#define DEPTH 8

typedef _Float16 f16;
typedef f16 h2 __attribute__((ext_vector_type(2)));

struct MaskSet {
  uint32_t M[DEPTH][NQ];   // M[l][b] = column b of W_l (pairing masks)
  uint32_t F[DEPTH][NQ];   // F[l][b] = row b of W_l^-1 (orientation functionals)
  uint32_t fz;             // final Z functional (row 24 of W_8^-1)
};

__host__ __device__ constexpr MaskSet buildMasks() {
  MaskSet r{};
  uint32_t col[NQ] = {}, inv[NQ] = {};
  for (int j = 0; j < NQ; ++j) { col[j] = 1u << j; inv[j] = 1u << j; }
  for (int l = 0; l < DEPTH; ++l) {
    for (int b = 0; b < NQ; ++b) { r.M[l][b] = col[b]; r.F[l][b] = inv[b]; }
    for (int w = 0; w < NQ - 1; ++w) {   // CNOT chain of layer l
      const int cb = 24 - w, tb = 23 - w;
      col[cb] ^= col[tb];
      inv[tb] ^= inv[cb];
    }
  }
  r.fz = inv[24];
  return r;
}

constexpr MaskSet MK = buildMasks();

// Half-index swizzle for 2^15-half LDS (kpassB): XOR bits 3..5 with 6..8.
__host__ __device__ constexpr uint32_t hswz(uint32_t h) { return h ^ ((h >> 3) & 0x38u); }

__host__ __device__ constexpr uint32_t kxorB(int L, int d0, uint32_t y) {
  uint32_t a = 0;
  for (int i = 0; i < 5; ++i) if ((y >> i) & 1u) a ^= MK.M[L][d0 + i];
  return a;
}

__host__ __device__ constexpr uint32_t cpar(uint32_t x) {
  uint32_t p = 0;
  for (int i = 0; i < 32; ++i) p ^= (x >> i) & 1u;
  return p;
}

// Evenness functional for R2's low-bit: bit0 of B2(t) = parity(t & r2mask(L)).
__host__ __device__ constexpr uint32_t r2mask(int L) {
  uint32_t r = 0;
  for (int i = 0; i < 5; ++i) {
    r |= (MK.M[L][i] & 1u) << i;           // t bits 0..4 -> dims 0..4
    r |= (MK.M[L][5 + i] & 1u) << (5 + i); // t bits 5..9 -> dims 5..9
  }
  return r;
}

__device__ __forceinline__ h2 h2bc(uint32_t u) { return __builtin_bit_cast(h2, u); }
__device__ __forceinline__ uint32_t u32bc(h2 x) { return __builtin_bit_cast(uint32_t, x); }
__device__ __forceinline__ h2 hswap(h2 x) { return __builtin_shufflevector(x, x, 1, 0); }
__device__ __forceinline__ h2 hset(float a, float b) { return (h2){ (f16)a, (f16)b }; }
__device__ __forceinline__ h2 hfma(h2 a, h2 b, h2 c) { return a * b + c; }

__global__ void kprep(const float* __restrict__ theta, float* __restrict__ trig,
                      float* __restrict__ outp)
{
  int t = threadIdx.x;
  if (t == 0) outp[0] = 0.0f;
  if (t < 200) {
    int l = t / 25, b = t % 25;            // b = bit position, qubit w = 24-b
    float th = theta[l * 25 + (24 - b)] * 0.5f;
    trig[2 * t]     = cosf(th);
    trig[2 * t + 1] = sinf(th);
  }
}

// Packed rotation for register-space dims (mask = 1<<j in register index,
// pack = register bit 0): uniform se, sigma(e) = bit j of e.
template<int JLO>
__device__ __forceinline__ void rot_pow2h(h2 (&q)[16], const float2* cs,
                                          const float* se5)
{
#pragma unroll
  for (int j = 0; j < 5; ++j) {
    const float c = cs[JLO + j].x;
    const float se = se5[j];
    const h2 c2 = hset(c, c);
    if (j == 0) {
      const h2 sv = hset(-se, se);
#pragma unroll
      for (uint32_t g = 0; g < 16; ++g)
        q[g] = hfma(sv, hswap(q[g]), c2 * q[g]);
    } else {
      const h2 sP = hset(se, se), sM = hset(-se, -se);
      const uint32_t mh = 1u << (j - 1);
#pragma unroll
      for (uint32_t g = 0; g < 16; ++g) {
        const uint32_t h = g ^ mh;
        if (h < g) continue;
        const h2 a = q[g], b = q[h];
        q[g] = hfma(sM, b, c2 * a);
        q[h] = hfma(sP, a, c2 * b);
      }
    }
  }
}

// ---- passB tail: R0 (general 5-bit masks) -> fp16 LDS (b128 write) -> R1
//      (u16 pair reads) -> writeback (no pre-barrier; bijective slots) ->
//      R2 -> merged full-wave dword stores (bit-blend). 2 barriers total.
template<int L>
__device__ __forceinline__ void passB_tail(h2 (&q)[16], uint16_t* ldsH,
                                           const uint32_t t, const uint32_t bb,
                                           const float* __restrict__ trig,
                                           uint16_t* __restrict__ stateH)
{
  const float2* cs = (const float2*)(trig + 50 * L);
  // R0: dims 0..4, masks M[L][j]&31 (general), sigma(e) = parity(e & fj5).
#pragma unroll
  for (int j = 0; j < 5; ++j) {
    const float2 w = cs[j];
    const float c = w.x, s = w.y;
    const float se = (__builtin_popcount((bb | (t << 5)) & MK.F[L][j]) & 1) ? -s : s;
    const uint32_t mmj = MK.M[L][j] & 31u;
    const uint32_t fj5 = MK.F[L][j] & 31u;
    const uint32_t mh = mmj >> 1;
    const bool sw = (mmj & 1u) != 0u;
    const h2 c2 = hset(c, c);
    const h2 sOdd = (fj5 & 1u) ? hset(se, -se) : hset(se, se);
    const h2 sEvn = (fj5 & 1u) ? hset(-se, se) : hset(-se, -se);
#pragma unroll
    for (uint32_t g = 0; g < 16; ++g) {
      const uint32_t h = g ^ mh;
      if (h < g) continue;
      const h2 a = q[g], b = q[h];
      const h2 pa = sw ? hswap(b) : b;
      const h2 sa = (__builtin_popcount(g & (fj5 >> 1)) & 1) ? sOdd : sEvn;
      q[g] = hfma(sa, pa, c2 * a);
      if (h != g) {
        const h2 pb = sw ? hswap(a) : a;
        const h2 sb2 = (__builtin_popcount(h & (fj5 >> 1)) & 1) ? sOdd : sEvn;
        q[h] = hfma(sb2, pb, c2 * b);
      }
    }
  }
  // exchange 1: own segment, 8 halves per b128 (hswz layout) — pure bitcast
  {
    uint4* l4 = (uint4*)ldsH;
#pragma unroll
    for (uint32_t k = 0; k < 4; ++k) {
      uint4 d = { u32bc(q[4*k+0]), u32bc(q[4*k+1]), u32bc(q[4*k+2]), u32bc(q[4*k+3]) };
      l4[hswz((t << 5) + 8u * k) >> 3] = d;
    }
  }
  __syncthreads();
  // R1: dims 5..9; thread coords: dims 0..4 <- t bits 0..4, dims 10..14 <- t bits 5..9
  uint32_t B1 = 0u;
#pragma unroll
  for (int i = 0; i < 5; ++i) B1 ^= ((t >> i) & 1u) ? MK.M[L][i] : 0u;
#pragma unroll
  for (int i = 0; i < 5; ++i) B1 ^= ((t >> (5 + i)) & 1u) ? MK.M[L][10 + i] : 0u;
  const uint32_t B1s = hswz(B1);
#pragma unroll
  for (uint32_t g = 0; g < 16; ++g) {
    const uint32_t lo = ldsH[B1s ^ hswz(kxorB(L, 5, 2*g))];
    const uint32_t hi = ldsH[B1s ^ hswz(kxorB(L, 5, 2*g+1))];
    q[g] = h2bc(lo | (hi << 16));
  }
  {
    float se5[5];
#pragma unroll
    for (int j = 0; j < 5; ++j) {
      const float s = cs[5 + j].y;
      se5[j] = (__builtin_popcount(bb & MK.F[L][5 + j]) & 1) ? -s : s;
    }
    rot_pow2h<5>(q, cs, se5);
  }
  // writeback to own read slots — no barrier needed before (bijective slots)
#pragma unroll
  for (uint32_t g = 0; g < 16; ++g) {
    const uint32_t u = u32bc(q[g]);
    ldsH[B1s ^ hswz(kxorB(L, 5, 2*g))]   = (uint16_t)u;
    ldsH[B1s ^ hswz(kxorB(L, 5, 2*g+1))] = (uint16_t)(u >> 16);
  }
  __syncthreads();
  // R2: dims 10..14; thread coords: dims 0..4 <- t bits 0..4, dims 5..9 <- t bits 5..9
  uint32_t B2 = 0u;
#pragma unroll
  for (int i = 0; i < 5; ++i) B2 ^= ((t >> i) & 1u) ? MK.M[L][i] : 0u;
#pragma unroll
  for (int i = 0; i < 5; ++i) B2 ^= ((t >> (5 + i)) & 1u) ? MK.M[L][5 + i] : 0u;
  const uint32_t B2s = hswz(B2);
#pragma unroll
  for (uint32_t g = 0; g < 16; ++g) {
    const uint32_t lo = ldsH[B2s ^ hswz(kxorB(L, 10, 2*g))];
    const uint32_t hi = ldsH[B2s ^ hswz(kxorB(L, 10, 2*g+1))];
    q[g] = h2bc(lo | (hi << 16));
  }
  {
    float se5[5];
#pragma unroll
    for (int j = 0; j < 5; ++j) {
      const float s = cs[10 + j].y;
      se5[j] = (__builtin_popcount(bb & MK.F[L][10 + j]) & 1) ? -s : s;
    }
    rot_pow2h<10>(q, cs, se5);
  }
  // merged store: pair (2g, 2g+1) via M[L][10]; cls = bit0 of own address;
  // partner lane = t^1 (M[L][0]=e0). One dword shfl + bit-blend per pair.
  {
    constexpr uint32_t rm = r2mask(L);
    const uint32_t cls = (uint32_t)__builtin_popcount(t & rm) & 1u;
    const uint32_t sb = bb ^ B2;
#pragma unroll
    for (uint32_t g = 0; g < 16; ++g) {
      const uint32_t d = u32bc(q[g]);
      const uint32_t p = (uint32_t)__shfl_xor((int)d, 1, 64);
      const uint32_t ad = (sb ^ kxorB(L, 10, 2*g) ^ (cls ? MK.M[L][10] : 0u)) & ~1u;
      const uint32_t val = cls ? ((p >> 16) | (d & 0xffff0000u))
                               : ((d & 0xffffu) | (p << 16));
      *(uint32_t*)(stateH + ad) = val;
    }
  }
}

template<int L>
__global__ __launch_bounds__(1024, 8) void kpassB(uint16_t* __restrict__ stateH,
                                                  const float* __restrict__ trig)
{
  __shared__ __align__(16) uint16_t ldsH[32768];   // 64 KiB -> 2 blocks/CU
  const uint32_t t = threadIdx.x;
  const uint32_t bb = (uint32_t)blockIdx.x << 15;
  // direct load: thread t owns 64 contiguous bytes (32 halves, tile order)
  h2 q[16];
  {
    const uint4* g4 = (const uint4*)(stateH + bb + (t << 5));
#pragma unroll
    for (uint32_t k = 0; k < 4; ++k) {
      const uint4 d = g4[k];
      q[4*k+0] = h2bc(d.x); q[4*k+1] = h2bc(d.y);
      q[4*k+2] = h2bc(d.z); q[4*k+3] = h2bc(d.w);
    }
  }
  passB_tail<L>(q, ldsH, t, bb, trig, stateH);
}

// kinit: layer-0 product state built analytically in tile-address order,
// then layer-1 passB tail. Write-only pass. Tree in f32, pack to h2 last.
__global__ __launch_bounds__(1024, 8) void kinit(uint16_t* __restrict__ stateH,
                                                 const float* __restrict__ trig)
{
  __shared__ __align__(16) uint16_t ldsH[32768];
  const uint32_t t = threadIdx.x;
  const uint32_t bb = (uint32_t)blockIdx.x << 15;
  const float2* cs0 = (const float2*)trig;       // layer 0, indexed by bit
  const uint32_t hi = bb | (t << 5);
  float pt = 1.0f;
#pragma unroll
  for (int b = 5; b < 25; ++b) {
    const float2 w = cs0[b];
    pt *= ((hi >> b) & 1u) ? w.y : w.x;
  }
  // f32 tree over element bits 1..4 (g bits 0..3), then bit 0 into halves
  float v16[16];
  v16[0] = pt;
#pragma unroll
  for (int j = 1; j < 5; ++j) {
    const float2 w = cs0[j];
#pragma unroll
    for (int g = 0; g < (1 << (j - 1)); ++g) {
      v16[g | (1 << (j - 1))] = v16[g] * w.y;
      v16[g] = v16[g] * w.x;
    }
  }
  h2 q[16];
  {
    const float2 w0 = cs0[0];
#pragma unroll
    for (int g = 0; g < 16; ++g) q[g] = hset(v16[g] * w0.x, v16[g] * w0.y);
  }
  passB_tail<1>(q, ldsH, t, bb, trig, stateH);
}

// ---- passA: pivots 15..24. Block = 32 contiguous spectators (slo) x 1024
// combos. NEW: stage the block's 64-KiB footprint into LDS with 4 dwordx4
// loads/thread (16B/lane), then R0 fragment reads from LDS, rotate, bijective
// writeback (no barrier), barrier, R1, merged stores. 2 barriers total.
// Stage layout: LDS half-index = (y<<5) | slo, y = combo index (bit i of y
// <-> mask M[L][15+i]).
template<int L, bool FIN>
__global__ __launch_bounds__(1024, 8) void kpassA(uint16_t* __restrict__ stateH,
                                                  const float* __restrict__ trig,
                                                  float* __restrict__ outp)
{
  __shared__ __align__(16) uint16_t ldsH[32768];   // 64 KiB
  __shared__ float wsum[16];
  const uint32_t t = threadIdx.x;
  const uint32_t sbase = (uint32_t)blockIdx.x << 5;   // bits 5..14
  const float2* cs = (const float2*)(trig + 50 * L) + 15;
  const uint32_t slo = t & 31u;
  const uint32_t yf  = t >> 5;
  const uint32_t odd = t & 1u;
  // ---- stage: y = (k<<8) | (t>>2); lane quad (t&3) covers 8 halves.
  // LDS half-index = (y<<5) + (t&3)*8 = (k<<13) + 8t  -> b128 writes.
  {
    uint32_t cb8 = 0u;
#pragma unroll
    for (int i = 0; i < 8; ++i)
      cb8 ^= (((t >> 2) >> i) & 1u) ? MK.M[L][15 + i] : 0u;
    const uint32_t qoff = (t & 3u) << 3;
    uint4* l4 = (uint4*)ldsH;
#pragma unroll
    for (uint32_t k = 0; k < 4; ++k) {
      const uint32_t Kk = ((k & 1u) ? MK.M[L][23] : 0u) ^ ((k & 2u) ? MK.M[L][24] : 0u);
      const uint4 d = *(const uint4*)(stateH + ((sbase ^ cb8 ^ Kk) | qoff));
      l4[((k << 13) + (t << 3)) >> 3] = d;
    }
  }
  __syncthreads();
  // ---- R0: register dims = pivots 15..19 (y bits 0..4); yf = y bits 5..9.
  h2 q[16];
  {
    const uint32_t rb0 = (yf << 10) + slo;
#pragma unroll
    for (uint32_t g = 0; g < 16; ++g) {
      const uint32_t lo = ldsH[rb0 + ((2*g) << 5)];
      const uint32_t hi = ldsH[rb0 + ((2*g+1) << 5)];
      q[g] = h2bc(lo | (hi << 16));
    }
  }
  {
    float se5[5];
#pragma unroll
    for (int j = 0; j < 5; ++j) se5[j] = cs[j].y;
    rot_pow2h<0>(q, cs, se5);
  }
  // writeback to own read slots (bijective: only thread (yf,slo) touches them)
  {
    const uint32_t rb0 = (yf << 10) + slo;
#pragma unroll
    for (uint32_t g = 0; g < 16; ++g) {
      const uint32_t u = u32bc(q[g]);
      ldsH[rb0 + ((2*g) << 5)]   = (uint16_t)u;
      ldsH[rb0 + ((2*g+1) << 5)] = (uint16_t)(u >> 16);
    }
  }
  __syncthreads();
  // ---- R1: register dims = pivots 20..24 (y bits 5..9); yf -> y bits 0..4.
  uint32_t cumt = 0u;
#pragma unroll
  for (int k = 0; k < 5; ++k) cumt ^= ((yf >> k) & 1u) ? MK.M[L][15 + k] : 0u;
  const uint32_t Ab = sbase ^ slo ^ cumt;
  {
    const uint32_t rb = (yf << 5) + slo;
#pragma unroll
    for (uint32_t g = 0; g < 16; ++g) {
      const uint32_t lo = ldsH[rb + ((2*g) << 10)];
      const uint32_t hi = ldsH[rb + ((2*g+1) << 10)];
      q[g] = h2bc(lo | (hi << 16));
    }
  }
  {
    float se5[5];
#pragma unroll
    for (int j = 0; j < 5; ++j) se5[j] = cs[5 + j].y;
    rot_pow2h<5>(q, cs, se5);
  }
  if (!FIN) {
    // merged stores: pair (2g, 2g+1) via M[L][20]; 1 dword shfl + blend.
#pragma unroll
    for (uint32_t g = 0; g < 16; ++g) {
      const uint32_t d = u32bc(q[g]);
      const uint32_t p = (uint32_t)__shfl_xor((int)d, 1, 64);
      const uint32_t ad = (Ab ^ kxorB(L, 20, 2*g) ^ (odd ? MK.M[L][20] : 0u)) & ~1u;
      const uint32_t val = odd ? ((p >> 16) | (d & 0xffff0000u))
                               : ((d & 0xffffu) | (p << 16));
      *(uint32_t*)(stateH + ad) = val;
    }
  } else {
    constexpr uint32_t pz =
        (cpar(MK.M[L][20] & MK.fz) << 0) | (cpar(MK.M[L][21] & MK.fz) << 1) |
        (cpar(MK.M[L][22] & MK.fz) << 2) | (cpar(MK.M[L][23] & MK.fz) << 3) |
        (cpar(MK.M[L][24] & MK.fz) << 4);
    float acc = 0.0f;
#pragma unroll
    for (uint32_t g = 0; g < 16; ++g) {
      const float x = (float)q[g].x;
      const float y = (float)q[g].y;
      acc += cpar((2*g) & pz)   ? -(x * x) : (x * x);
      acc += cpar((2*g+1) & pz) ? -(y * y) : (y * y);
    }
    if (__builtin_popcount(Ab & MK.fz) & 1) acc = -acc;
#pragma unroll
    for (int off = 32; off >= 1; off >>= 1) acc += __shfl_down(acc, off, 64);
    if ((t & 63u) == 0u) wsum[t >> 6] = acc;
    __syncthreads();
    if (t == 0) {
      float ssum = 0.0f;
#pragma unroll
      for (int w2 = 0; w2 < 16; ++w2) ssum += wsum[w2];
      atomicAdd(outp, ssum);
    }
  }
}

extern "C" void kernel_launch(void* const* d_in, const int* in_sizes, int n_in,
                              void* d_out, int out_size, void* d_ws, size_t ws_size,
                              hipStream_t stream)
{
  (void)in_sizes; (void)n_in; (void)out_size; (void)ws_size;
  const float* theta = (const float*)d_in[0];
  float* outp  = (float*)d_out;
  uint16_t* stateH = (uint16_t*)d_ws;                              // 2^25 halves
  float* trig  = (float*)((char*)d_ws + (size_t)(1u << 25) * 2u);  // 400 floats

  kprep<<<1, 256, 0, stream>>>(theta, trig, outp);
  kinit<<<1024, 1024, 0, stream>>>(stateH, trig);
  kpassA<1, false><<<1024, 1024, 0, stream>>>(stateH, trig, outp);
  kpassB<2><<<1024, 1024, 0, stream>>>(stateH, trig);
  kpassA<2, false><<<1024, 1024, 0, stream>>>(stateH, trig, outp);
  kpassB<3><<<1024, 1024, 0, stream>>>(stateH, trig);
  kpassA<3, false><<<1024, 1024, 0, stream>>>(stateH, trig, outp);
  kpassB<4><<<1024, 1024, 0, stream>>>(stateH, trig);
  kpassA<4, false><<<1024, 1024, 0, stream>>>(stateH, trig, outp);
  kpassB<5><<<1024, 1024, 0, stream>>>(stateH, trig);
  kpassA<5, false><<<1024, 1024, 0, stream>>>(stateH, trig, outp);
  kpassB<6><<<1024, 1024, 0, stream>>>(stateH, trig);
  kpassA<6, false><<<1024, 1024, 0, stream>>>(stateH, trig, outp);
  kpassB<7><<<1024, 1024, 0, stream>>>(stateH, trig);
  kpassA<7, true><<<1024, 1024, 0, stream>>>(stateH, trig, outp);
}